// Round 5
// baseline (1647.808 us; speedup 1.0000x reference)
//
#include <hip/hip_runtime.h>
#include <hip/hip_bf16.h>
#include <math.h>

#define PI_F 3.14159265358979323846f

static constexpr int F = 128;
static constexpr int KB = 30;      // sinc basis size
static constexpr int LAYERS = 3;
static constexpr float CUT = 4.0f;
static constexpr int BINS = 512;   // table bins; rows = BINS+1
static constexpr int TROW = 512;   // packed table row stride (floats): 128 lanes * 4 slots

typedef short bf16x8 __attribute__((ext_vector_type(8)));
typedef float f32x4 __attribute__((ext_vector_type(4)));

__device__ __forceinline__ float bf2f(unsigned short u) {
    union { unsigned int i; float f; } c; c.i = ((unsigned int)u) << 16; return c.f;
}
__device__ __forceinline__ short f2bf(float x) {
    union { float f; unsigned int u; } c; c.f = x;
    unsigned int r = c.u + 0x7FFFu + ((c.u >> 16) & 1u);
    return (short)(r >> 16);
}

__device__ __forceinline__ float edge_dist(const float* __restrict__ sxyz,
                                           const float* __restrict__ dxyz,
                                           const float* __restrict__ disp,
                                           const float* __restrict__ cell,
                                           int s, int d, int e, float* dx) {
    const float* dp = disp + 3 * (size_t)e;
#pragma unroll
    for (int i = 0; i < 3; i++) {
        float dc = dp[0] * cell[0 * 3 + i] + dp[1] * cell[1 * 3 + i] + dp[2] * cell[2 * 3 + i];
        dx[i] = dxyz[3 * d + i] - (sxyz[3 * s + i] + dc);
    }
    return sqrtf(dx[0] * dx[0] + dx[1] * dx[1] + dx[2] * dx[2]);
}

// ---------------- CSR build (cutoff-filtered) ----------------
__global__ void k_count(const int* __restrict__ edges, const float* __restrict__ sxyz,
                        const float* __restrict__ dxyz, const float* __restrict__ disp,
                        const float* __restrict__ cell, int* __restrict__ cnt, int E) {
    int i = blockIdx.x * blockDim.x + threadIdx.x;
    if (i >= E) return;
    int s = edges[2 * i], d = edges[2 * i + 1];
    float dx[3];
    float dist = edge_dist(sxyz, dxyz, disp, cell, s, d, i, dx);
    if (dist < CUT) atomicAdd(&cnt[d], 1);
}

__global__ void k_scan(const int* __restrict__ cnt, int* __restrict__ off, int n) {
    __shared__ int part[1024];
    int t = threadIdx.x;
    int chunk = (n + 1023) / 1024;
    int b = t * chunk; if (b > n) b = n;
    int e = b + chunk; if (e > n) e = n;
    int s = 0;
    for (int i = b; i < e; i++) s += cnt[i];
    part[t] = s;
    __syncthreads();
    for (int o = 1; o < 1024; o <<= 1) {
        int v = part[t];
        int add = (t >= o) ? part[t - o] : 0;
        __syncthreads();
        part[t] = v + add;
        __syncthreads();
    }
    int run = (t == 0) ? 0 : part[t - 1];
    for (int i = b; i < e; i++) { off[i] = run; run += cnt[i]; }
    if (t == 1023) off[n] = part[1023];
}

__global__ void k_scatter(const int* __restrict__ edges, const float* __restrict__ sxyz,
                          const float* __restrict__ dxyz, const float* __restrict__ disp,
                          const float* __restrict__ cell, int* __restrict__ cur,
                          int* __restrict__ eids, int E) {
    int i = blockIdx.x * blockDim.x + threadIdx.x;
    if (i >= E) return;
    int s = edges[2 * i], d = edges[2 * i + 1];
    float dx[3];
    float dist = edge_dist(sxyz, dxyz, disp, cell, s, d, i, dx);
    if (dist < CUT) {
        int pos = atomicAdd(&cur[d], 1);
        eids[pos] = i;
    }
}

// ---------------- edge records, CSR-ordered: float4(u0,u1,u2, dist*BINS/CUT) ----------------
__global__ void k_geom_rec(const float* __restrict__ sxyz, const float* __restrict__ dxyz,
                           const float* __restrict__ disp, const float* __restrict__ cell,
                           const int* __restrict__ edges, const int* __restrict__ eids,
                           const int* __restrict__ eoff, int ndst,
                           float4* __restrict__ erec, int* __restrict__ srcs) {
    int pos = blockIdx.x * blockDim.x + threadIdx.x;
    if (pos >= eoff[ndst]) return;
    int e = eids[pos];
    int s = edges[2 * e], d = edges[2 * e + 1];
    float dx[3];
    float dist = edge_dist(sxyz, dxyz, disp, cell, s, d, e, dx);
    float inv = 1.0f / fmaxf(dist, 1e-12f);
    float db = fminf(dist * ((float)BINS / CUT), (float)BINS - 0.0001f);
    erec[pos] = make_float4(dx[0] * inv, dx[1] * inv, dx[2] * inv, db);
    srcs[pos] = s;
}

// ---------------- S' basis: S'(i,k) = cc_i * st_k(d_i), S'(i,30)=cc_i, S'(i,31)=0 ----------------
__global__ void k_sbuild(float* __restrict__ Sp) {
    int i = blockIdx.x * blockDim.x + threadIdx.x;
    if (i > BINS) return;
    float d = (float)i * (CUT / (float)BINS);
    float cc = (d < CUT) ? 0.5f * (cosf(PI_F * d / CUT) + 1.0f) : 0.0f;
    float* row = Sp + (size_t)i * 32;
#pragma unroll
    for (int k = 0; k < KB; k++) {
        float kk = (float)(k + 1);
        float st = (d > 1e-12f) ? sinf(PI_F * d * kk / CUT) / d : PI_F * kk / CUT;
        row[k] = cc * st;
    }
    row[30] = cc;
    row[31] = 0.f;
}

// ---------------- assemble fw' (6 tables x 32 x 384) ----------------
__global__ void k_fwpack(const float* __restrict__ ai_fw, const float* __restrict__ ai_fb,
                         const float* __restrict__ pm_fw, const float* __restrict__ pm_fb,
                         float* __restrict__ fwp) {
    int i = blockIdx.x * blockDim.x + threadIdx.x;
    if (i >= 6 * 32 * 384) return;
    int tbl = i / (32 * 384);
    int k = (i / 384) % 32;
    int c = i % 384;
    const float* fw = (tbl < 3) ? ai_fw + (size_t)tbl * KB * 384 : pm_fw + (size_t)(tbl - 3) * KB * 384;
    const float* fb = (tbl < 3) ? ai_fb + (size_t)tbl * 384 : pm_fb + (size_t)(tbl - 3) * 384;
    float v = 0.f;
    if (k < KB) v = fw[(size_t)k * 384 + c];
    else if (k == 30) v = fb[c];
    fwp[i] = v;
}

// ---------------- init: s0 = embed[Z] ----------------
__global__ void k_embed(const int* __restrict__ Z, const float* __restrict__ emb,
                        float* __restrict__ s, int n) {
    int i = blockIdx.x * blockDim.x + threadIdx.x;
    if (i < n * F) s[i] = emb[(size_t)Z[i / F] * F + (i % F)];
}

// ---------------- f32 VALU GEMM (kept for tiny table builds) ----------------
// outmode: 0 f32 flat, 3 f32 packed384 ([m][128][4], slot=(c>>7)).
__global__ __launch_bounds__(256) void k_gemm(const float* __restrict__ A, const float* __restrict__ B,
                                              const float* __restrict__ bias, void* __restrict__ Cout,
                                              int M, int N, int K, int act, int outmode) {
    __shared__ float As[16][64];
    __shared__ float Bs[16][64];
    int tid = threadIdx.x;
    int bm = blockIdx.y * 64, bn = blockIdx.x * 64;
    int tx = tid & 15, ty = tid >> 4;
    float acc[4][4] = {};
    int arow = tid >> 2;
    int acol = (tid & 3) * 4;
    int brow = tid >> 4;
    int bcol = (tid & 15) * 4;
    for (int k0 = 0; k0 < K; k0 += 16) {
        float4 av = make_float4(0.f, 0.f, 0.f, 0.f);
        int gm = bm + arow;
        if (gm < M) av = *reinterpret_cast<const float4*>(A + (size_t)gm * K + k0 + acol);
        As[acol + 0][arow] = av.x; As[acol + 1][arow] = av.y;
        As[acol + 2][arow] = av.z; As[acol + 3][arow] = av.w;
        float4 bv = *reinterpret_cast<const float4*>(B + (size_t)(k0 + brow) * N + bn + bcol);
        Bs[brow][bcol + 0] = bv.x; Bs[brow][bcol + 1] = bv.y;
        Bs[brow][bcol + 2] = bv.z; Bs[brow][bcol + 3] = bv.w;
        __syncthreads();
#pragma unroll
        for (int k = 0; k < 16; k++) {
            float a0 = As[k][ty * 4 + 0], a1 = As[k][ty * 4 + 1];
            float a2 = As[k][ty * 4 + 2], a3 = As[k][ty * 4 + 3];
            float b0 = Bs[k][tx * 4 + 0], b1 = Bs[k][tx * 4 + 1];
            float b2 = Bs[k][tx * 4 + 2], b3 = Bs[k][tx * 4 + 3];
            acc[0][0] += a0 * b0; acc[0][1] += a0 * b1; acc[0][2] += a0 * b2; acc[0][3] += a0 * b3;
            acc[1][0] += a1 * b0; acc[1][1] += a1 * b1; acc[1][2] += a1 * b2; acc[1][3] += a1 * b3;
            acc[2][0] += a2 * b0; acc[2][1] += a2 * b1; acc[2][2] += a2 * b2; acc[2][3] += a2 * b3;
            acc[3][0] += a3 * b0; acc[3][1] += a3 * b1; acc[3][2] += a3 * b2; acc[3][3] += a3 * b3;
        }
        __syncthreads();
    }
#pragma unroll
    for (int i = 0; i < 4; i++) {
        int gm = bm + ty * 4 + i;
        if (gm >= M) continue;
#pragma unroll
        for (int j = 0; j < 4; j++) {
            int gn = bn + tx * 4 + j;
            float v = acc[i][j];
            if (bias) v += bias[gn];
            if (act == 1) v = v / (1.0f + expf(-v));
            else if (act == 2) v = 1.0f / (1.0f + expf(-v));
            if (outmode == 0) ((float*)Cout)[(size_t)gm * N + gn] = v;
            else ((float*)Cout)[(size_t)gm * 512 + (gn & 127) * 4 + (gn >> 7)] = v;
        }
    }
}

// ---------------- bf16 MFMA GEMM: C = act(A@B + bias) ----------------
// A (M,K) f32 rm, B (K,N) f32 rm. Requires N%128==0, K%32==0.
// act: 0 none, 1 silu, 2 sigmoid. outmode: 0 f32 flat, 2 bf16 packed384.
__global__ __launch_bounds__(256) void k_gemm_mfma(const float* __restrict__ A,
                                                   const float* __restrict__ B,
                                                   const float* __restrict__ bias,
                                                   void* __restrict__ Cout,
                                                   int M, int N, int K, int act, int outmode) {
    __shared__ short As[128][40];   // [m][k], pad 32->40 (2-way bank alias only)
    __shared__ short Bs[128][40];   // transposed: [n][k]
    const int tid = threadIdx.x;
    const int lane = tid & 63;
    const int wave = tid >> 6;
    const int wr = wave >> 1, wc = wave & 1;
    const int bm = blockIdx.y * 128, bn = blockIdx.x * 128;
    const int l15 = lane & 15, l16 = lane >> 4;   // l16 in 0..3
    f32x4 acc[4][4] = {};

    for (int k0 = 0; k0 < K; k0 += 32) {
        // stage A: 128x32 f32 -> bf16
#pragma unroll
        for (int j = 0; j < 4; j++) {
            int idx = tid + 256 * j;
            int row = idx >> 3, kq = (idx & 7) * 4;
            float4 av = make_float4(0.f, 0.f, 0.f, 0.f);
            int gm = bm + row;
            if (gm < M) av = *reinterpret_cast<const float4*>(A + (size_t)gm * K + k0 + kq);
            short4 sv; sv.x = f2bf(av.x); sv.y = f2bf(av.y); sv.z = f2bf(av.z); sv.w = f2bf(av.w);
            *reinterpret_cast<short4*>(&As[row][kq]) = sv;
        }
        // stage B transposed: 32x128 f32 -> Bs[n][k]
#pragma unroll
        for (int j = 0; j < 4; j++) {
            int idx = tid + 256 * j;
            int krow = idx >> 5, nq = (idx & 31) * 4;
            float4 bv = *reinterpret_cast<const float4*>(B + (size_t)(k0 + krow) * N + bn + nq);
            Bs[nq + 0][krow] = f2bf(bv.x);
            Bs[nq + 1][krow] = f2bf(bv.y);
            Bs[nq + 2][krow] = f2bf(bv.z);
            Bs[nq + 3][krow] = f2bf(bv.w);
        }
        __syncthreads();
        bf16x8 af[4], bfr[4];
#pragma unroll
        for (int f = 0; f < 4; f++) {
            af[f]  = *reinterpret_cast<const bf16x8*>(&As[wr * 64 + f * 16 + l15][l16 * 8]);
            bfr[f] = *reinterpret_cast<const bf16x8*>(&Bs[wc * 64 + f * 16 + l15][l16 * 8]);
        }
#pragma unroll
        for (int i = 0; i < 4; i++)
#pragma unroll
            for (int j = 0; j < 4; j++)
                acc[i][j] = __builtin_amdgcn_mfma_f32_16x16x32_bf16(af[i], bfr[j], acc[i][j], 0, 0, 0);
        __syncthreads();
    }

#pragma unroll
    for (int j = 0; j < 4; j++) {
        int gn = bn + wc * 64 + j * 16 + l15;
        float bb = bias ? bias[gn] : 0.f;
#pragma unroll
        for (int i = 0; i < 4; i++) {
#pragma unroll
            for (int r = 0; r < 4; r++) {
                int gm = bm + wr * 64 + i * 16 + l16 * 4 + r;
                if (gm >= M) continue;
                float v = acc[i][j][r] + bb;
                if (act == 1) v = v / (1.0f + expf(-v));
                else if (act == 2) v = 1.0f / (1.0f + expf(-v));
                if (outmode == 0) ((float*)Cout)[(size_t)gm * N + gn] = v;
                else ((short*)Cout)[(size_t)gm * 512 + (gn & 127) * 4 + (gn >> 7)] = f2bf(v);
            }
        }
    }
}

// ---------------- fused edge messages + segment sum (table-driven) ----------------
__global__ __launch_bounds__(256) void k_gather(
    const float4* __restrict__ erec, const int* __restrict__ srcs,
    const int* __restrict__ eoff, const float* __restrict__ T,
    const __hip_bfloat16* __restrict__ phi, const __hip_bfloat16* __restrict__ vsend,
    const float* __restrict__ s_in, const float* __restrict__ v_in,
    float* __restrict__ s_out, float* __restrict__ v_out, int ndst) {
    const int t = threadIdx.x & 127;     // column owner: t, t+128, t+256
    const int half = threadIdx.x >> 7;   // 2 destinations per block
    const float4* __restrict__ T4 = reinterpret_cast<const float4*>(T);

    for (int d = blockIdx.x * 2 + half; d < ndst; d += gridDim.x * 2) {
        const int e0 = eoff[d], e1 = eoff[d + 1];
        float accs = 0.f, av0 = 0.f, av1 = 0.f, av2 = 0.f;

        auto body = [&](int ii) {
            const int src = srcs[ii];
            const float4 u = erec[ii];
            const int bin = (int)u.w;
            const float fr = u.w - (float)bin;
            const float4 ta = T4[(size_t)bin * 128 + t];
            const float4 tb = T4[(size_t)(bin + 1) * 128 + t];
            const ushort4 ph = *reinterpret_cast<const ushort4*>(phi + (size_t)src * 512 + t * 4);
            const ushort4 vs = *reinterpret_cast<const ushort4*>(vsend + (size_t)src * 512 + t * 4);
            const float f0 = fmaf(fr, tb.x - ta.x, ta.x);
            const float f1 = fmaf(fr, tb.y - ta.y, ta.y);
            const float f2 = fmaf(fr, tb.z - ta.z, ta.z);
            const float gsv = f0 * bf2f(ph.x);
            const float gev = f1 * bf2f(ph.y);
            const float gss = f2 * bf2f(ph.z);
            accs += gss;
            av0 = fmaf(bf2f(vs.x), gsv, fmaf(gev, u.x, av0));
            av1 = fmaf(bf2f(vs.y), gsv, fmaf(gev, u.y, av1));
            av2 = fmaf(bf2f(vs.z), gsv, fmaf(gev, u.z, av2));
        };

        int ii = e0;
        for (; ii + 1 < e1; ii += 2) { body(ii); body(ii + 1); }
        if (ii < e1) body(ii);

        if (s_in) {
            accs += s_in[(size_t)d * 128 + t];
            av0 += v_in[(size_t)d * 384 + t];
            av1 += v_in[(size_t)d * 384 + 128 + t];
            av2 += v_in[(size_t)d * 384 + 256 + t];
        }
        s_out[(size_t)d * 128 + t] = accs;
        v_out[(size_t)d * 384 + t] = av0;
        v_out[(size_t)d * 384 + 128 + t] = av1;
        v_out[(size_t)d * 384 + 256 + t] = av2;
    }
}

// ---------------- cat = [s, ||Vv||_axis1] ----------------
__global__ void k_catnorm(const float* __restrict__ s, const float* __restrict__ Vv,
                          float* __restrict__ cat, int n) {
    int i = blockIdx.x * blockDim.x + threadIdx.x;
    if (i >= n * F) return;
    int nn = i / F, g = i % F;
    size_t b = (size_t)nn * 384;
    float w0 = Vv[b + g], w1 = Vv[b + 128 + g], w2 = Vv[b + 256 + g];
    cat[(size_t)nn * 256 + g] = s[i];
    cat[(size_t)nn * 256 + 128 + g] = sqrtf(w0 * w0 + w1 * w1 + w2 * w2);
}

// ---------------- painn update (optionally emit packed-bf16 copy of v_out) ----------------
__global__ void k_update(const float* __restrict__ s_in, const float* __restrict__ v_in,
                         const float* __restrict__ a, const float* __restrict__ Uv,
                         const float* __restrict__ Vv,
                         float* __restrict__ s_out, float* __restrict__ v_out,
                         __hip_bfloat16* __restrict__ v_out_bf, int n) {
    int i = blockIdx.x * blockDim.x + threadIdx.x;
    if (i >= n * F) return;
    int nn = i / F, g = i % F;
    size_t b = (size_t)nn * 384;
    float u0 = Uv[b + g], u1 = Uv[b + 128 + g], u2 = Uv[b + 256 + g];
    float w0 = Vv[b + g], w1 = Vv[b + 128 + g], w2 = Vv[b + 256 + g];
    float inner = u0 * w0 + u1 * w1 + u2 * w2;
    float ass = a[b + g], asv = a[b + 128 + g], avv = a[b + 256 + g];
    s_out[i] = s_in[i] + ass + asv * inner;
    float r0 = v_in[b + g] + avv * u0;
    float r1 = v_in[b + 128 + g] + avv * u1;
    float r2 = v_in[b + 256 + g] + avv * u2;
    v_out[b + g] = r0;
    v_out[b + 128 + g] = r1;
    v_out[b + 256 + g] = r2;
    if (v_out_bf) {
        size_t pb = (size_t)nn * 512 + (size_t)g * 4;
        v_out_bf[pb + 0] = __float2bfloat16(r0);
        v_out_bf[pb + 1] = __float2bfloat16(r1);
        v_out_bf[pb + 2] = __float2bfloat16(r2);
    }
}

// ---------------- gated blend ----------------
__global__ void k_blend(const float* __restrict__ gate, const float* __restrict__ ms,
                        const float* __restrict__ mv, float* __restrict__ ps,
                        float* __restrict__ pv, int n) {
    int i = blockIdx.x * blockDim.x + threadIdx.x;
    if (i >= n * F) return;
    int p = i / F, g = i % F;
    float gs = gate[(size_t)p * 256 + g];
    float gv = gate[(size_t)p * 256 + 128 + g];
    ps[i] = ps[i] * gs + (1.0f - gs) * ms[i];
    size_t b = (size_t)p * 384;
#pragma unroll
    for (int i3 = 0; i3 < 3; i3++) {
        size_t o = b + (size_t)i3 * 128 + g;
        pv[o] = pv[o] * gv + (1.0f - gv) * mv[o];
    }
}

extern "C" void kernel_launch(void* const* d_in, const int* in_sizes, int n_in,
                              void* d_out, int out_size, void* d_ws, size_t ws_size,
                              hipStream_t stream) {
    const float* atom_xyz  = (const float*)d_in[0];
    const float* probe_xyz = (const float*)d_in[1];
    const float* cell      = (const float*)d_in[2];
    const float* a_disp    = (const float*)d_in[3];
    const float* p_disp    = (const float*)d_in[4];
    const float* atom_embed= (const float*)d_in[5];
    const float* ai_fw = (const float*)d_in[6];
    const float* ai_fb = (const float*)d_in[7];
    const float* ai_w1 = (const float*)d_in[8];
    const float* ai_b1 = (const float*)d_in[9];
    const float* ai_w2 = (const float*)d_in[10];
    const float* ai_b2 = (const float*)d_in[11];
    const float* au_U  = (const float*)d_in[12];
    const float* au_V  = (const float*)d_in[13];
    const float* au_w1 = (const float*)d_in[14];
    const float* au_b1 = (const float*)d_in[15];
    const float* au_w2 = (const float*)d_in[16];
    const float* au_b2 = (const float*)d_in[17];
    const float* pm_fw = (const float*)d_in[18];
    const float* pm_fb = (const float*)d_in[19];
    const float* pm_w1 = (const float*)d_in[20];
    const float* pm_b1 = (const float*)d_in[21];
    const float* pm_w2 = (const float*)d_in[22];
    const float* pm_b2 = (const float*)d_in[23];
    const float* pm_gw1= (const float*)d_in[24];
    const float* pm_gb1= (const float*)d_in[25];
    const float* pm_gw2= (const float*)d_in[26];
    const float* pm_gb2= (const float*)d_in[27];
    const float* pu_U  = (const float*)d_in[28];
    const float* pu_V  = (const float*)d_in[29];
    const float* pu_w1 = (const float*)d_in[30];
    const float* pu_b1 = (const float*)d_in[31];
    const float* pu_w2 = (const float*)d_in[32];
    const float* pu_b2 = (const float*)d_in[33];
    const int* nodes_Z = (const int*)d_in[34];
    const int* a_edges = (const int*)d_in[35];
    const int* p_edges = (const int*)d_in[36];

    const int N  = in_sizes[34];
    const int EA = in_sizes[35] / 2;
    const int EP = in_sizes[36] / 2;
    const int P  = in_sizes[1] / 3;

    char* w = (char*)d_ws;
    size_t off = 0;
    auto alloc = [&](size_t bytes) -> void* {
        void* p = w + off;
        off = (off + bytes + 255) & ~(size_t)255;
        return p;
    };
    int* a_off  = (int*)alloc((size_t)(N + 1) * 4);
    int* a_cur  = (int*)alloc((size_t)N * 4);
    int* a_eids = (int*)alloc((size_t)EA * 4);
    int* a_srcs = (int*)alloc((size_t)EA * 4);
    int* p_off  = (int*)alloc((size_t)(P + 1) * 4);
    int* p_cur  = (int*)alloc((size_t)P * 4);
    int* p_eids = (int*)alloc((size_t)EP * 4);
    int* p_srcs = (int*)alloc((size_t)EP * 4);
    float4* a_erec = (float4*)alloc((size_t)EA * 16);
    float4* p_erec = (float4*)alloc((size_t)EP * 16);
    float* Sp   = (float*)alloc((size_t)(BINS + 1) * 32 * 4);
    float* fwp  = (float*)alloc((size_t)6 * 32 * 384 * 4);
    float* Tpack= (float*)alloc((size_t)6 * (BINS + 1) * TROW * 4);
    float* s0     = (float*)alloc((size_t)N * F * 4);
    float* v0     = (float*)alloc((size_t)N * 3 * F * 4);
    float* s_list = (float*)alloc((size_t)LAYERS * N * F * 4);
    float* v_list = (float*)alloc((size_t)LAYERS * N * 3 * F * 4);
    float* ms     = (float*)alloc((size_t)P * F * 4);
    float* mv     = (float*)alloc((size_t)P * 3 * F * 4);
    float* hbuf   = (float*)alloc((size_t)P * 2 * F * 4);
    float* Uv     = (float*)alloc((size_t)P * 3 * F * 4);
    float* Vv     = (float*)alloc((size_t)P * 3 * F * 4);
    float* cat    = (float*)alloc((size_t)P * 2 * F * 4);
    float* abuf   = (float*)alloc((size_t)P * 3 * F * 4);
    float* gatebuf= (float*)alloc((size_t)P * 2 * F * 4);
    __hip_bfloat16* phi_bf   = (__hip_bfloat16*)alloc((size_t)N * 512 * 2);
    __hip_bfloat16* v0_bf    = (__hip_bfloat16*)alloc((size_t)N * 512 * 2);
    __hip_bfloat16* v_list_bf= (__hip_bfloat16*)alloc((size_t)LAYERS * N * 512 * 2);
    (void)ws_size; (void)n_in;

    // CSR atoms (cutoff-filtered)
    hipMemsetAsync(a_cur, 0, (size_t)N * 4, stream);
    k_count<<<(EA + 255) / 256, 256, 0, stream>>>(a_edges, atom_xyz, atom_xyz, a_disp, cell, a_cur, EA);
    k_scan<<<1, 1024, 0, stream>>>(a_cur, a_off, N);
    hipMemcpyAsync(a_cur, a_off, (size_t)N * 4, hipMemcpyDeviceToDevice, stream);
    k_scatter<<<(EA + 255) / 256, 256, 0, stream>>>(a_edges, atom_xyz, atom_xyz, a_disp, cell, a_cur, a_eids, EA);
    // CSR probes
    hipMemsetAsync(p_cur, 0, (size_t)P * 4, stream);
    k_count<<<(EP + 255) / 256, 256, 0, stream>>>(p_edges, atom_xyz, probe_xyz, p_disp, cell, p_cur, EP);
    k_scan<<<1, 1024, 0, stream>>>(p_cur, p_off, P);
    hipMemcpyAsync(p_cur, p_off, (size_t)P * 4, hipMemcpyDeviceToDevice, stream);
    k_scatter<<<(EP + 255) / 256, 256, 0, stream>>>(p_edges, atom_xyz, probe_xyz, p_disp, cell, p_cur, p_eids, EP);

    // edge records (CSR-ordered)
    k_geom_rec<<<(EA + 255) / 256, 256, 0, stream>>>(atom_xyz, atom_xyz, a_disp, cell, a_edges,
                                                     a_eids, a_off, N, a_erec, a_srcs);
    k_geom_rec<<<(EP + 255) / 256, 256, 0, stream>>>(atom_xyz, probe_xyz, p_disp, cell, p_edges,
                                                     p_eids, p_off, P, p_erec, p_srcs);

    // filter tables: T_tbl = S' @ fw'_tbl (cc and fb folded), packed f32 [bin][128][4]
    k_sbuild<<<(BINS + 256) / 256, 256, 0, stream>>>(Sp);
    k_fwpack<<<(6 * 32 * 384 + 255) / 256, 256, 0, stream>>>(ai_fw, ai_fb, pm_fw, pm_fb, fwp);
    for (int tbl = 0; tbl < 6; tbl++) {
        dim3 g(384 / 64, (BINS + 1 + 63) / 64);
        k_gemm<<<g, 256, 0, stream>>>(Sp, fwp + (size_t)tbl * 32 * 384, nullptr,
                                      Tpack + (size_t)tbl * (BINS + 1) * TROW,
                                      BINS + 1, 384, 32, 0, 3);
    }

    // init node states
    k_embed<<<(N * F + 255) / 256, 256, 0, stream>>>(nodes_Z, atom_embed, s0, N);
    hipMemsetAsync(v0, 0, (size_t)N * 3 * F * 4, stream);
    hipMemsetAsync(v0_bf, 0, (size_t)N * 512 * 2, stream);

    // MFMA GEMM for all model matmuls (N%128==0, K%32==0)
    auto gemm = [&](const float* A, const float* B, const float* bias, void* C,
                    int M, int Nc, int K, int act, int outmode = 0) {
        dim3 g(Nc / 128, (M + 127) / 128);
        k_gemm_mfma<<<g, 256, 0, stream>>>(A, B, bias, C, M, Nc, K, act, outmode);
    };

    // ---- atom message-passing layers ----
    for (int l = 0; l < LAYERS; l++) {
        const float* scur = l ? (s_list + (size_t)(l - 1) * N * F) : s0;
        const float* vcur = l ? (v_list + (size_t)(l - 1) * N * 3 * F) : v0;
        const __hip_bfloat16* vcur_bf = l ? (v_list_bf + (size_t)(l - 1) * N * 512) : v0_bf;
        gemm(scur, ai_w1 + (size_t)l * F * F, ai_b1 + (size_t)l * F, hbuf, N, F, F, 1);
        gemm(hbuf, ai_w2 + (size_t)l * F * 3 * F, ai_b2 + (size_t)l * 3 * F, phi_bf, N, 3 * F, F, 0, 2);
        k_gather<<<(N + 1) / 2, 256, 0, stream>>>(a_erec, a_srcs, a_off,
                                        Tpack + (size_t)l * (BINS + 1) * TROW,
                                        phi_bf, vcur_bf, scur, vcur, ms, mv, N);
        gemm(mv, au_U + (size_t)l * F * F, nullptr, Uv, 3 * N, F, F, 0);
        gemm(mv, au_V + (size_t)l * F * F, nullptr, Vv, 3 * N, F, F, 0);
        k_catnorm<<<(N * F + 255) / 256, 256, 0, stream>>>(ms, Vv, cat, N);
        gemm(cat, au_w1 + (size_t)l * 2 * F * F, au_b1 + (size_t)l * F, hbuf, N, F, 2 * F, 1);
        gemm(hbuf, au_w2 + (size_t)l * F * 3 * F, au_b2 + (size_t)l * 3 * F, abuf, N, 3 * F, F, 0);
        k_update<<<(N * F + 255) / 256, 256, 0, stream>>>(ms, mv, abuf, Uv, Vv,
                  s_list + (size_t)l * N * F, v_list + (size_t)l * N * 3 * F,
                  v_list_bf + (size_t)l * N * 512, N);
    }

    // ---- probe phase ----
    float* ps = (float*)d_out;
    float* pv = (float*)d_out + (size_t)P * F;
    hipMemsetAsync(d_out, 0, (size_t)out_size * 4, stream);

    for (int l = 0; l < LAYERS; l++) {
        const float* sl = s_list + (size_t)l * N * F;
        const __hip_bfloat16* vl_bf = v_list_bf + (size_t)l * N * 512;
        gemm(sl, pm_w1 + (size_t)l * F * F, pm_b1 + (size_t)l * F, hbuf, N, F, F, 1);
        gemm(hbuf, pm_w2 + (size_t)l * F * 3 * F, pm_b2 + (size_t)l * 3 * F, phi_bf, N, 3 * F, F, 0, 2);
        k_gather<<<(P + 1) / 2, 256, 0, stream>>>(p_erec, p_srcs, p_off,
                                        Tpack + (size_t)(3 + l) * (BINS + 1) * TROW,
                                        phi_bf, vl_bf, nullptr, nullptr, ms, mv, P);
        gemm(ms, pm_gw1 + (size_t)l * F * 2 * F, pm_gb1 + (size_t)l * 2 * F, hbuf, P, 2 * F, F, 1);
        gemm(hbuf, pm_gw2 + (size_t)l * 2 * F * 2 * F, pm_gb2 + (size_t)l * 2 * F, gatebuf, P, 2 * F, 2 * F, 2);
        k_blend<<<(P * F + 255) / 256, 256, 0, stream>>>(gatebuf, ms, mv, ps, pv, P);
        gemm(pv, pu_U + (size_t)l * F * F, nullptr, Uv, 3 * P, F, F, 0);
        gemm(pv, pu_V + (size_t)l * F * F, nullptr, Vv, 3 * P, F, F, 0);
        k_catnorm<<<(P * F + 255) / 256, 256, 0, stream>>>(ps, Vv, cat, P);
        gemm(cat, pu_w1 + (size_t)l * 2 * F * F, pu_b1 + (size_t)l * F, hbuf, P, F, 2 * F, 1);
        gemm(hbuf, pu_w2 + (size_t)l * F * 3 * F, pu_b2 + (size_t)l * 3 * F, abuf, P, 3 * F, F, 0);
        k_update<<<(P * F + 255) / 256, 256, 0, stream>>>(ps, pv, abuf, Uv, Vv, ps, pv, nullptr, P);
    }
}

// Round 6
// 1212.335 us; speedup vs baseline: 1.3592x; 1.3592x over previous
//
#include <hip/hip_runtime.h>
#include <hip/hip_bf16.h>
#include <math.h>

#define PI_F 3.14159265358979323846f

static constexpr int F = 128;
static constexpr int KB = 30;      // sinc basis size
static constexpr int LAYERS = 3;
static constexpr float CUT = 4.0f;
static constexpr int BINS = 512;   // table bins; rows = BINS+1

typedef short bf16x8 __attribute__((ext_vector_type(8)));
typedef float f32x4 __attribute__((ext_vector_type(4)));

__device__ __forceinline__ float bf2f(unsigned short u) {
    union { unsigned int i; float f; } c; c.i = ((unsigned int)u) << 16; return c.f;
}
__device__ __forceinline__ short f2bf(float x) {
    union { float f; unsigned int u; } c; c.f = x;
    unsigned int r = c.u + 0x7FFFu + ((c.u >> 16) & 1u);
    return (short)(r >> 16);
}

__device__ __forceinline__ float edge_dist(const float* __restrict__ sxyz,
                                           const float* __restrict__ dxyz,
                                           const float* __restrict__ disp,
                                           const float* __restrict__ cell,
                                           int s, int d, int e, float* dx) {
    const float* dp = disp + 3 * (size_t)e;
#pragma unroll
    for (int i = 0; i < 3; i++) {
        float dc = dp[0] * cell[0 * 3 + i] + dp[1] * cell[1 * 3 + i] + dp[2] * cell[2 * 3 + i];
        dx[i] = dxyz[3 * d + i] - (sxyz[3 * s + i] + dc);
    }
    return sqrtf(dx[0] * dx[0] + dx[1] * dx[1] + dx[2] * dx[2]);
}

// ---------------- CSR build (cutoff-filtered) ----------------
__global__ void k_count(const int* __restrict__ edges, const float* __restrict__ sxyz,
                        const float* __restrict__ dxyz, const float* __restrict__ disp,
                        const float* __restrict__ cell, int* __restrict__ cnt, int E) {
    int i = blockIdx.x * blockDim.x + threadIdx.x;
    if (i >= E) return;
    int s = edges[2 * i], d = edges[2 * i + 1];
    float dx[3];
    float dist = edge_dist(sxyz, dxyz, disp, cell, s, d, i, dx);
    if (dist < CUT) atomicAdd(&cnt[d], 1);
}

__global__ void k_scan(const int* __restrict__ cnt, int* __restrict__ off, int n) {
    __shared__ int part[1024];
    int t = threadIdx.x;
    int chunk = (n + 1023) / 1024;
    int b = t * chunk; if (b > n) b = n;
    int e = b + chunk; if (e > n) e = n;
    int s = 0;
    for (int i = b; i < e; i++) s += cnt[i];
    part[t] = s;
    __syncthreads();
    for (int o = 1; o < 1024; o <<= 1) {
        int v = part[t];
        int add = (t >= o) ? part[t - o] : 0;
        __syncthreads();
        part[t] = v + add;
        __syncthreads();
    }
    int run = (t == 0) ? 0 : part[t - 1];
    for (int i = b; i < e; i++) { off[i] = run; run += cnt[i]; }
    if (t == 1023) off[n] = part[1023];
}

__global__ void k_scatter(const int* __restrict__ edges, const float* __restrict__ sxyz,
                          const float* __restrict__ dxyz, const float* __restrict__ disp,
                          const float* __restrict__ cell, int* __restrict__ cur,
                          int* __restrict__ eids, int E) {
    int i = blockIdx.x * blockDim.x + threadIdx.x;
    if (i >= E) return;
    int s = edges[2 * i], d = edges[2 * i + 1];
    float dx[3];
    float dist = edge_dist(sxyz, dxyz, disp, cell, s, d, i, dx);
    if (dist < CUT) {
        int pos = atomicAdd(&cur[d], 1);
        eids[pos] = i;
    }
}

// ---------------- edge records, CSR-ordered: float4(u0,u1,u2, dist*BINS/CUT) ----------------
__global__ void k_geom_rec(const float* __restrict__ sxyz, const float* __restrict__ dxyz,
                           const float* __restrict__ disp, const float* __restrict__ cell,
                           const int* __restrict__ edges, const int* __restrict__ eids,
                           const int* __restrict__ eoff, int ndst,
                           float4* __restrict__ erec, int* __restrict__ srcs) {
    int pos = blockIdx.x * blockDim.x + threadIdx.x;
    if (pos >= eoff[ndst]) return;
    int e = eids[pos];
    int s = edges[2 * e], d = edges[2 * e + 1];
    float dx[3];
    float dist = edge_dist(sxyz, dxyz, disp, cell, s, d, e, dx);
    float inv = 1.0f / fmaxf(dist, 1e-12f);
    float db = fminf(dist * ((float)BINS / CUT), (float)BINS - 0.0001f);
    erec[pos] = make_float4(dx[0] * inv, dx[1] * inv, dx[2] * inv, db);
    srcs[pos] = s;
}

// ---------------- S' basis ----------------
__global__ void k_sbuild(float* __restrict__ Sp) {
    int i = blockIdx.x * blockDim.x + threadIdx.x;
    if (i > BINS) return;
    float d = (float)i * (CUT / (float)BINS);
    float cc = (d < CUT) ? 0.5f * (cosf(PI_F * d / CUT) + 1.0f) : 0.0f;
    float* row = Sp + (size_t)i * 32;
#pragma unroll
    for (int k = 0; k < KB; k++) {
        float kk = (float)(k + 1);
        float st = (d > 1e-12f) ? sinf(PI_F * d * kk / CUT) / d : PI_F * kk / CUT;
        row[k] = cc * st;
    }
    row[30] = cc;
    row[31] = 0.f;
}

// ---------------- assemble fw' (6 tables x 32 x 384) ----------------
__global__ void k_fwpack(const float* __restrict__ ai_fw, const float* __restrict__ ai_fb,
                         const float* __restrict__ pm_fw, const float* __restrict__ pm_fb,
                         float* __restrict__ fwp) {
    int i = blockIdx.x * blockDim.x + threadIdx.x;
    if (i >= 6 * 32 * 384) return;
    int tbl = i / (32 * 384);
    int k = (i / 384) % 32;
    int c = i % 384;
    const float* fw = (tbl < 3) ? ai_fw + (size_t)tbl * KB * 384 : pm_fw + (size_t)(tbl - 3) * KB * 384;
    const float* fb = (tbl < 3) ? ai_fb + (size_t)tbl * 384 : pm_fb + (size_t)(tbl - 3) * 384;
    float v = 0.f;
    if (k < KB) v = fw[(size_t)k * 384 + c];
    else if (k == 30) v = fb[c];
    fwp[i] = v;
}

// ---------------- weight transpose+cvt: src f32 [K][N] (xL) -> dst bf16 [N][K] ----------------
struct CvtArgs {
    const float* src[14];
    int dstoff[14];
    int Kk[14];
    int Nn[14];
};
__global__ __launch_bounds__(256) void k_cvtw(CvtArgs a, short* __restrict__ dst) {
    int arr = blockIdx.y, l = blockIdx.z;
    int K = a.Kk[arr], N = a.Nn[arr];
    int tilesx = N / 32, tilesy = K / 32;
    int tile = blockIdx.x;
    if (tile >= tilesx * tilesy) return;
    int tn = (tile % tilesx) * 32, tk = (tile / tilesx) * 32;
    __shared__ float tb[32][33];
    int tx = threadIdx.x & 31, ty = threadIdx.x >> 5;  // 32 x 8
    const float* src = a.src[arr] + (size_t)l * K * N;
    short* d = dst + a.dstoff[arr] + (size_t)l * K * N;
#pragma unroll
    for (int r = 0; r < 4; r++)
        tb[ty * 4 + r][tx] = src[(size_t)(tk + ty * 4 + r) * N + tn + tx];
    __syncthreads();
#pragma unroll
    for (int r = 0; r < 4; r++)
        d[(size_t)(tn + ty * 4 + r) * K + tk + tx] = f2bf(tb[tx][ty * 4 + r]);
}

// ---------------- init: s0 = embed[Z] (f32 + bf16) ----------------
__global__ void k_embed(const int* __restrict__ Z, const float* __restrict__ emb,
                        float* __restrict__ s, short* __restrict__ sbf, int n) {
    int i = blockIdx.x * blockDim.x + threadIdx.x;
    if (i < n * F) {
        float v = emb[(size_t)Z[i / F] * F + (i % F)];
        s[i] = v; sbf[i] = f2bf(v);
    }
}

// ---------------- f32 VALU GEMM (table build only) ----------------
// outmode: 0 f32 flat, 4 bf16 packed512. blockIdx.z selects B/C via strides.
__global__ __launch_bounds__(256) void k_gemm(const float* __restrict__ A, const float* __restrict__ B,
                                              void* __restrict__ Cout,
                                              int M, int N, int K, int outmode,
                                              int bstride, int cstride) {
    __shared__ float As[16][64];
    __shared__ float Bs[16][64];
    const float* Bz = B + (size_t)blockIdx.z * bstride;
    int tid = threadIdx.x;
    int bm = blockIdx.y * 64, bn = blockIdx.x * 64;
    int tx = tid & 15, ty = tid >> 4;
    float acc[4][4] = {};
    int arow = tid >> 2;
    int acol = (tid & 3) * 4;
    int brow = tid >> 4;
    int bcol = (tid & 15) * 4;
    for (int k0 = 0; k0 < K; k0 += 16) {
        float4 av = make_float4(0.f, 0.f, 0.f, 0.f);
        int gm = bm + arow;
        if (gm < M) av = *reinterpret_cast<const float4*>(A + (size_t)gm * K + k0 + acol);
        As[acol + 0][arow] = av.x; As[acol + 1][arow] = av.y;
        As[acol + 2][arow] = av.z; As[acol + 3][arow] = av.w;
        float4 bv = *reinterpret_cast<const float4*>(Bz + (size_t)(k0 + brow) * N + bn + bcol);
        Bs[brow][bcol + 0] = bv.x; Bs[brow][bcol + 1] = bv.y;
        Bs[brow][bcol + 2] = bv.z; Bs[brow][bcol + 3] = bv.w;
        __syncthreads();
#pragma unroll
        for (int k = 0; k < 16; k++) {
            float a0 = As[k][ty * 4 + 0], a1 = As[k][ty * 4 + 1];
            float a2 = As[k][ty * 4 + 2], a3 = As[k][ty * 4 + 3];
            float b0 = Bs[k][tx * 4 + 0], b1 = Bs[k][tx * 4 + 1];
            float b2 = Bs[k][tx * 4 + 2], b3 = Bs[k][tx * 4 + 3];
            acc[0][0] += a0 * b0; acc[0][1] += a0 * b1; acc[0][2] += a0 * b2; acc[0][3] += a0 * b3;
            acc[1][0] += a1 * b0; acc[1][1] += a1 * b1; acc[1][2] += a1 * b2; acc[1][3] += a1 * b3;
            acc[2][0] += a2 * b0; acc[2][1] += a2 * b1; acc[2][2] += a2 * b2; acc[2][3] += a2 * b3;
            acc[3][0] += a3 * b0; acc[3][1] += a3 * b1; acc[3][2] += a3 * b2; acc[3][3] += a3 * b3;
        }
        __syncthreads();
    }
#pragma unroll
    for (int i = 0; i < 4; i++) {
        int gm = bm + ty * 4 + i;
        if (gm >= M) continue;
#pragma unroll
        for (int j = 0; j < 4; j++) {
            int gn = bn + tx * 4 + j;
            float v = acc[i][j];
            if (outmode == 0) ((float*)Cout)[(size_t)gm * N + gn] = v;
            else ((short*)Cout)[(size_t)blockIdx.z * cstride + (size_t)gm * 512 + (gn & 127) * 4 + (gn >> 7)] = f2bf(v);
        }
    }
}

// ---------------- bf16 MFMA GEMM, weights-stationary-in-cache, no LDS/barriers ----------------
// A: [M][K] bf16 rm. Bt: [N][K] bf16 rm (pre-transposed weights). N%64==0, K%32==0.
// Wave = 64 rows x 64 cols; block = 4 waves stacked (256 rows x 64 cols).
// act: 0 none, 1 silu, 2 sigmoid. outmode: 0 f32 flat, 1 bf16 flat, 2 bf16 packed512.
// blockIdx.z==1 -> use Bt2/C2 (fused dual GEMM sharing A).
__global__ __launch_bounds__(256) void k_gemm2(
    const short* __restrict__ A, const short* __restrict__ Bt,
    const float* __restrict__ bias, void* __restrict__ C,
    int M, int N, int K, int act, int outmode,
    const short* __restrict__ Bt2, void* __restrict__ C2) {
    const short* __restrict__ B = (blockIdx.z && Bt2) ? Bt2 : Bt;
    void* __restrict__ Co = (blockIdx.z && C2) ? C2 : C;
    const int lane = threadIdx.x & 63, wave = threadIdx.x >> 6;
    const int l15 = lane & 15, l16 = lane >> 4;
    const int row0 = blockIdx.y * 256 + wave * 64;
    const int col0 = blockIdx.x * 64;
    if (row0 >= M) return;
    f32x4 acc[4][4] = {};
    for (int k0 = 0; k0 < K; k0 += 32) {
        bf16x8 af[4], bfr[4];
#pragma unroll
        for (int i = 0; i < 4; i++) {
            int r = row0 + i * 16 + l15;
            bf16x8 t = {};
            if (r < M) t = *reinterpret_cast<const bf16x8*>(A + (size_t)r * K + k0 + l16 * 8);
            af[i] = t;
        }
#pragma unroll
        for (int j = 0; j < 4; j++) {
            int c = col0 + j * 16 + l15;
            bfr[j] = *reinterpret_cast<const bf16x8*>(B + (size_t)c * K + k0 + l16 * 8);
        }
#pragma unroll
        for (int i = 0; i < 4; i++)
#pragma unroll
            for (int j = 0; j < 4; j++)
                acc[i][j] = __builtin_amdgcn_mfma_f32_16x16x32_bf16(af[i], bfr[j], acc[i][j], 0, 0, 0);
    }
#pragma unroll
    for (int j = 0; j < 4; j++) {
        int gn = col0 + j * 16 + l15;
        float bb = bias ? bias[gn] : 0.f;
#pragma unroll
        for (int i = 0; i < 4; i++) {
#pragma unroll
            for (int r = 0; r < 4; r++) {
                int gm = row0 + i * 16 + l16 * 4 + r;
                if (gm >= M) continue;
                float v = acc[i][j][r] + bb;
                if (act == 1) v = v / (1.0f + expf(-v));
                else if (act == 2) v = 1.0f / (1.0f + expf(-v));
                if (outmode == 0) ((float*)Co)[(size_t)gm * N + gn] = v;
                else if (outmode == 1) ((short*)Co)[(size_t)gm * N + gn] = f2bf(v);
                else ((short*)Co)[(size_t)gm * 512 + (gn & 127) * 4 + (gn >> 7)] = f2bf(v);
            }
        }
    }
}

// ---------------- fused edge messages + segment sum (bf16 table) ----------------
__global__ __launch_bounds__(256) void k_gather(
    const float4* __restrict__ erec, const int* __restrict__ srcs,
    const int* __restrict__ eoff, const short* __restrict__ T,
    const short* __restrict__ phi, const short* __restrict__ vsend,
    const float* __restrict__ s_in, const float* __restrict__ v_in,
    float* __restrict__ s_out, float* __restrict__ v_out,
    short* __restrict__ s_out_bf, short* __restrict__ v_out_bf, int ndst) {
    const int t = threadIdx.x & 127;
    const int half = threadIdx.x >> 7;

    for (int d = blockIdx.x * 2 + half; d < ndst; d += gridDim.x * 2) {
        const int e0 = eoff[d], e1 = eoff[d + 1];
        float accs = 0.f, av0 = 0.f, av1 = 0.f, av2 = 0.f;

        auto body = [&](int ii) {
            const int src = srcs[ii];
            const float4 u = erec[ii];
            const int bin = (int)u.w;
            const float fr = u.w - (float)bin;
            const ushort4 ta = *reinterpret_cast<const ushort4*>(T + (size_t)bin * 512 + t * 4);
            const ushort4 tb = *reinterpret_cast<const ushort4*>(T + (size_t)(bin + 1) * 512 + t * 4);
            const ushort4 ph = *reinterpret_cast<const ushort4*>(phi + (size_t)src * 512 + t * 4);
            const ushort4 vs = *reinterpret_cast<const ushort4*>(vsend + (size_t)src * 512 + t * 4);
            float a0 = bf2f(ta.x), a1 = bf2f(ta.y), a2 = bf2f(ta.z);
            const float f0 = fmaf(fr, bf2f(tb.x) - a0, a0);
            const float f1 = fmaf(fr, bf2f(tb.y) - a1, a1);
            const float f2 = fmaf(fr, bf2f(tb.z) - a2, a2);
            const float gsv = f0 * bf2f(ph.x);
            const float gev = f1 * bf2f(ph.y);
            const float gss = f2 * bf2f(ph.z);
            accs += gss;
            av0 = fmaf(bf2f(vs.x), gsv, fmaf(gev, u.x, av0));
            av1 = fmaf(bf2f(vs.y), gsv, fmaf(gev, u.y, av1));
            av2 = fmaf(bf2f(vs.z), gsv, fmaf(gev, u.z, av2));
        };

        int ii = e0;
        for (; ii + 1 < e1; ii += 2) { body(ii); body(ii + 1); }
        if (ii < e1) body(ii);

        if (s_in) {
            accs += s_in[(size_t)d * 128 + t];
            av0 += v_in[(size_t)d * 384 + t];
            av1 += v_in[(size_t)d * 384 + 128 + t];
            av2 += v_in[(size_t)d * 384 + 256 + t];
        }
        if (s_out) {
            s_out[(size_t)d * 128 + t] = accs;
            v_out[(size_t)d * 384 + t] = av0;
            v_out[(size_t)d * 384 + 128 + t] = av1;
            v_out[(size_t)d * 384 + 256 + t] = av2;
        }
        if (s_out_bf) s_out_bf[(size_t)d * 128 + t] = f2bf(accs);
        if (v_out_bf) {
            v_out_bf[(size_t)(3 * d + 0) * 128 + t] = f2bf(av0);
            v_out_bf[(size_t)(3 * d + 1) * 128 + t] = f2bf(av1);
            v_out_bf[(size_t)(3 * d + 2) * 128 + t] = f2bf(av2);
        }
    }
}

// ---------------- cat = [s, ||Vv||_axis1] -> bf16 ----------------
__global__ void k_catnorm(const float* __restrict__ s, const short* __restrict__ Vv,
                          short* __restrict__ cat, int n) {
    int i = blockIdx.x * blockDim.x + threadIdx.x;
    if (i >= n * F) return;
    int nn = i / F, g = i % F;
    float w0 = bf2f(Vv[(size_t)(3 * nn + 0) * 128 + g]);
    float w1 = bf2f(Vv[(size_t)(3 * nn + 1) * 128 + g]);
    float w2 = bf2f(Vv[(size_t)(3 * nn + 2) * 128 + g]);
    cat[(size_t)nn * 256 + g] = f2bf(s[i]);
    cat[(size_t)nn * 256 + 128 + g] = f2bf(sqrtf(w0 * w0 + w1 * w1 + w2 * w2));
}

// ---------------- painn update ----------------
__global__ void k_update(const float* __restrict__ s_in, const float* __restrict__ v_in,
                         const short* __restrict__ a, const short* __restrict__ Uv,
                         const short* __restrict__ Vv,
                         float* __restrict__ s_out, float* __restrict__ v_out,
                         short* __restrict__ s_out_bf, short* __restrict__ v_out_pk, int n) {
    int i = blockIdx.x * blockDim.x + threadIdx.x;
    if (i >= n * F) return;
    int nn = i / F, g = i % F;
    size_t b = (size_t)nn * 384;
    float u0 = bf2f(Uv[(size_t)(3 * nn + 0) * 128 + g]);
    float u1 = bf2f(Uv[(size_t)(3 * nn + 1) * 128 + g]);
    float u2 = bf2f(Uv[(size_t)(3 * nn + 2) * 128 + g]);
    float w0 = bf2f(Vv[(size_t)(3 * nn + 0) * 128 + g]);
    float w1 = bf2f(Vv[(size_t)(3 * nn + 1) * 128 + g]);
    float w2 = bf2f(Vv[(size_t)(3 * nn + 2) * 128 + g]);
    float inner = u0 * w0 + u1 * w1 + u2 * w2;
    float ass = bf2f(a[b + g]), asv = bf2f(a[b + 128 + g]), avv = bf2f(a[b + 256 + g]);
    float snew = s_in[i] + ass + asv * inner;
    s_out[i] = snew;
    float r0 = v_in[b + g] + avv * u0;
    float r1 = v_in[b + 128 + g] + avv * u1;
    float r2 = v_in[b + 256 + g] + avv * u2;
    v_out[b + g] = r0;
    v_out[b + 128 + g] = r1;
    v_out[b + 256 + g] = r2;
    if (s_out_bf) s_out_bf[i] = f2bf(snew);
    if (v_out_pk) {
        size_t pb = (size_t)nn * 512 + (size_t)g * 4;
        v_out_pk[pb + 0] = f2bf(r0);
        v_out_pk[pb + 1] = f2bf(r1);
        v_out_pk[pb + 2] = f2bf(r2);
    }
}

// ---------------- gated blend (bf16 gate/ms/mv; f32 ps/pv RMW; bf16 pv out) ----------------
__global__ void k_blend(const short* __restrict__ gate, const short* __restrict__ ms,
                        const short* __restrict__ mv, float* __restrict__ ps,
                        float* __restrict__ pv, short* __restrict__ pv_bf, int n) {
    int i = blockIdx.x * blockDim.x + threadIdx.x;
    if (i >= n * F) return;
    int p = i / F, g = i % F;
    float gs = bf2f(gate[(size_t)p * 256 + g]);
    float gv = bf2f(gate[(size_t)p * 256 + 128 + g]);
    ps[i] = ps[i] * gs + (1.0f - gs) * bf2f(ms[(size_t)p * 128 + g]);
    size_t b = (size_t)p * 384;
#pragma unroll
    for (int i3 = 0; i3 < 3; i3++) {
        size_t o = b + (size_t)i3 * 128 + g;
        float val = pv[o] * gv + (1.0f - gv) * bf2f(mv[(size_t)(3 * p + i3) * 128 + g]);
        pv[o] = val;
        pv_bf[(size_t)(3 * p + i3) * 128 + g] = f2bf(val);
    }
}

extern "C" void kernel_launch(void* const* d_in, const int* in_sizes, int n_in,
                              void* d_out, int out_size, void* d_ws, size_t ws_size,
                              hipStream_t stream) {
    const float* atom_xyz  = (const float*)d_in[0];
    const float* probe_xyz = (const float*)d_in[1];
    const float* cell      = (const float*)d_in[2];
    const float* a_disp    = (const float*)d_in[3];
    const float* p_disp    = (const float*)d_in[4];
    const float* atom_embed= (const float*)d_in[5];
    const float* ai_fw = (const float*)d_in[6];
    const float* ai_fb = (const float*)d_in[7];
    const float* ai_b1 = (const float*)d_in[9];
    const float* ai_b2 = (const float*)d_in[11];
    const float* au_b1 = (const float*)d_in[15];
    const float* au_b2 = (const float*)d_in[17];
    const float* pm_fw = (const float*)d_in[18];
    const float* pm_fb = (const float*)d_in[19];
    const float* pm_b1 = (const float*)d_in[21];
    const float* pm_b2 = (const float*)d_in[23];
    const float* pm_gb1= (const float*)d_in[25];
    const float* pm_gb2= (const float*)d_in[27];
    const float* pu_b1 = (const float*)d_in[31];
    const float* pu_b2 = (const float*)d_in[33];
    const int* nodes_Z = (const int*)d_in[34];
    const int* a_edges = (const int*)d_in[35];
    const int* p_edges = (const int*)d_in[36];

    const int N  = in_sizes[34];
    const int EA = in_sizes[35] / 2;
    const int EP = in_sizes[36] / 2;
    const int P  = in_sizes[1] / 3;

    // weight table: {src input idx, K, N}
    enum { W_AI_W1=0, W_AI_W2, W_AU_U, W_AU_V, W_AU_W1, W_AU_W2, W_PM_W1, W_PM_W2,
           W_PM_GW1, W_PM_GW2, W_PU_U, W_PU_V, W_PU_W1, W_PU_W2 };
    const int wsrc[14] = {8,10,12,13,14,16,20,22,24,26,28,29,30,32};
    const int wK[14]   = {128,128,128,128,256,128,128,128,128,256,128,128,256,128};
    const int wN[14]   = {128,384,128,128,128,384,128,384,256,256,128,128,128,384};
    size_t woff[15]; woff[0] = 0;
    for (int i = 0; i < 14; i++) woff[i + 1] = woff[i] + (size_t)3 * wK[i] * wN[i];

    char* w = (char*)d_ws;
    size_t off = 0;
    auto alloc = [&](size_t bytes) -> void* {
        void* p = w + off;
        off = (off + bytes + 255) & ~(size_t)255;
        return p;
    };
    int* a_off  = (int*)alloc((size_t)(N + 1) * 4);
    int* a_cur  = (int*)alloc((size_t)N * 4);
    int* a_eids = (int*)alloc((size_t)EA * 4);
    int* a_srcs = (int*)alloc((size_t)EA * 4);
    int* p_off  = (int*)alloc((size_t)(P + 1) * 4);
    int* p_cur  = (int*)alloc((size_t)P * 4);
    int* p_eids = (int*)alloc((size_t)EP * 4);
    int* p_srcs = (int*)alloc((size_t)EP * 4);
    float4* a_erec = (float4*)alloc((size_t)EA * 16);
    float4* p_erec = (float4*)alloc((size_t)EP * 16);
    float* Sp   = (float*)alloc((size_t)(BINS + 1) * 32 * 4);
    float* fwp  = (float*)alloc((size_t)6 * 32 * 384 * 4);
    short* Tbf  = (short*)alloc((size_t)6 * (BINS + 1) * 512 * 2);
    short* wbt  = (short*)alloc(woff[14] * 2);
    float* s0     = (float*)alloc((size_t)N * F * 4);
    float* v0     = (float*)alloc((size_t)N * 3 * F * 4);
    float* s_list = (float*)alloc((size_t)LAYERS * N * F * 4);
    float* v_list = (float*)alloc((size_t)LAYERS * N * 3 * F * 4);
    float* msf    = (float*)alloc((size_t)N * F * 4);
    float* mvf    = (float*)alloc((size_t)N * 3 * F * 4);
    short* s0_bf    = (short*)alloc((size_t)N * F * 2);
    short* sbf_list = (short*)alloc((size_t)LAYERS * N * F * 2);
    short* v0_pk    = (short*)alloc((size_t)N * 512 * 2);
    short* vpk_list = (short*)alloc((size_t)LAYERS * N * 512 * 2);
    short* phi_pk   = (short*)alloc((size_t)N * 512 * 2);
    short* ms_bf    = (short*)alloc((size_t)P * F * 2);
    short* mv_bf    = (short*)alloc((size_t)P * 3 * F * 2);
    short* h_bf     = (short*)alloc((size_t)P * 2 * F * 2);
    short* gate_bf  = (short*)alloc((size_t)P * 2 * F * 2);
    short* cat_bf   = (short*)alloc((size_t)P * 2 * F * 2);
    short* abuf_bf  = (short*)alloc((size_t)P * 3 * F * 2);
    short* Uv_bf    = (short*)alloc((size_t)P * 3 * F * 2);
    short* Vv_bf    = (short*)alloc((size_t)P * 3 * F * 2);
    short* pv_bf    = (short*)alloc((size_t)P * 3 * F * 2);
    (void)ws_size; (void)n_in;

    // CSR atoms (cutoff-filtered)
    hipMemsetAsync(a_cur, 0, (size_t)N * 4, stream);
    k_count<<<(EA + 255) / 256, 256, 0, stream>>>(a_edges, atom_xyz, atom_xyz, a_disp, cell, a_cur, EA);
    k_scan<<<1, 1024, 0, stream>>>(a_cur, a_off, N);
    hipMemcpyAsync(a_cur, a_off, (size_t)N * 4, hipMemcpyDeviceToDevice, stream);
    k_scatter<<<(EA + 255) / 256, 256, 0, stream>>>(a_edges, atom_xyz, atom_xyz, a_disp, cell, a_cur, a_eids, EA);
    // CSR probes
    hipMemsetAsync(p_cur, 0, (size_t)P * 4, stream);
    k_count<<<(EP + 255) / 256, 256, 0, stream>>>(p_edges, atom_xyz, probe_xyz, p_disp, cell, p_cur, EP);
    k_scan<<<1, 1024, 0, stream>>>(p_cur, p_off, P);
    hipMemcpyAsync(p_cur, p_off, (size_t)P * 4, hipMemcpyDeviceToDevice, stream);
    k_scatter<<<(EP + 255) / 256, 256, 0, stream>>>(p_edges, atom_xyz, probe_xyz, p_disp, cell, p_cur, p_eids, EP);

    // edge records (CSR-ordered)
    k_geom_rec<<<(EA + 255) / 256, 256, 0, stream>>>(atom_xyz, atom_xyz, a_disp, cell, a_edges,
                                                     a_eids, a_off, N, a_erec, a_srcs);
    k_geom_rec<<<(EP + 255) / 256, 256, 0, stream>>>(atom_xyz, probe_xyz, p_disp, cell, p_edges,
                                                     p_eids, p_off, P, p_erec, p_srcs);

    // filter tables (bf16 packed512), all 6 in one z-merged launch
    k_sbuild<<<(BINS + 256) / 256, 256, 0, stream>>>(Sp);
    k_fwpack<<<(6 * 32 * 384 + 255) / 256, 256, 0, stream>>>(ai_fw, ai_fb, pm_fw, pm_fb, fwp);
    {
        dim3 g(384 / 64, (BINS + 1 + 63) / 64, 6);
        k_gemm<<<g, 256, 0, stream>>>(Sp, fwp, Tbf, BINS + 1, 384, 32, 4, 32 * 384, (BINS + 1) * 512);
    }

    // weights -> bf16 transposed
    {
        CvtArgs ca;
        for (int i = 0; i < 14; i++) {
            ca.src[i] = (const float*)d_in[wsrc[i]];
            ca.dstoff[i] = (int)woff[i];
            ca.Kk[i] = wK[i]; ca.Nn[i] = wN[i];
        }
        k_cvtw<<<dim3(64, 14, 3), 256, 0, stream>>>(ca, wbt);
    }
    auto wt = [&](int a, int l) { return wbt + woff[a] + (size_t)l * wK[a] * wN[a]; };

    // init node states
    k_embed<<<(N * F + 255) / 256, 256, 0, stream>>>(nodes_Z, atom_embed, s0, s0_bf, N);
    hipMemsetAsync(v0, 0, (size_t)N * 3 * F * 4, stream);
    hipMemsetAsync(v0_pk, 0, (size_t)N * 512 * 2, stream);

    auto gemm2 = [&](const short* A, const short* Bt, const float* bias, void* C,
                     int M, int Nc, int K, int act, int outmode,
                     const short* Bt2 = nullptr, void* C2 = nullptr) {
        dim3 g(Nc / 64, (M + 255) / 256, Bt2 ? 2 : 1);
        k_gemm2<<<g, 256, 0, stream>>>(A, Bt, bias, C, M, Nc, K, act, outmode, Bt2, C2);
    };

    // ---- atom message-passing layers ----
    for (int l = 0; l < LAYERS; l++) {
        const float* scur = l ? (s_list + (size_t)(l - 1) * N * F) : s0;
        const float* vcur = l ? (v_list + (size_t)(l - 1) * N * 3 * F) : v0;
        const short* scur_bf = l ? (sbf_list + (size_t)(l - 1) * N * F) : s0_bf;
        const short* vcur_pk = l ? (vpk_list + (size_t)(l - 1) * N * 512) : v0_pk;
        gemm2(scur_bf, wt(W_AI_W1, l), ai_b1 + (size_t)l * F, h_bf, N, 128, 128, 1, 1);
        gemm2(h_bf, wt(W_AI_W2, l), ai_b2 + (size_t)l * 3 * F, phi_pk, N, 384, 128, 0, 2);
        k_gather<<<(N + 1) / 2, 256, 0, stream>>>(a_erec, a_srcs, a_off,
                 Tbf + (size_t)l * (BINS + 1) * 512, phi_pk, vcur_pk,
                 scur, vcur, msf, mvf, nullptr, mv_bf, N);
        gemm2(mv_bf, wt(W_AU_U, l), nullptr, Uv_bf, 3 * N, 128, 128, 0, 1,
              wt(W_AU_V, l), Vv_bf);
        k_catnorm<<<(N * F + 255) / 256, 256, 0, stream>>>(msf, Vv_bf, cat_bf, N);
        gemm2(cat_bf, wt(W_AU_W1, l), au_b1 + (size_t)l * F, h_bf, N, 128, 256, 1, 1);
        gemm2(h_bf, wt(W_AU_W2, l), au_b2 + (size_t)l * 3 * F, abuf_bf, N, 384, 128, 0, 1);
        k_update<<<(N * F + 255) / 256, 256, 0, stream>>>(msf, mvf, abuf_bf, Uv_bf, Vv_bf,
                 s_list + (size_t)l * N * F, v_list + (size_t)l * N * 3 * F,
                 sbf_list + (size_t)l * N * F, vpk_list + (size_t)l * N * 512, N);
    }

    // ---- probe phase ----
    float* ps = (float*)d_out;
    float* pv = (float*)d_out + (size_t)P * F;
    hipMemsetAsync(d_out, 0, (size_t)out_size * 4, stream);

    for (int l = 0; l < LAYERS; l++) {
        const short* sl_bf = sbf_list + (size_t)l * N * F;
        const short* vl_pk = vpk_list + (size_t)l * N * 512;
        gemm2(sl_bf, wt(W_PM_W1, l), pm_b1 + (size_t)l * F, h_bf, N, 128, 128, 1, 1);
        gemm2(h_bf, wt(W_PM_W2, l), pm_b2 + (size_t)l * 3 * F, phi_pk, N, 384, 128, 0, 2);
        k_gather<<<(P + 1) / 2, 256, 0, stream>>>(p_erec, p_srcs, p_off,
                 Tbf + (size_t)(3 + l) * (BINS + 1) * 512, phi_pk, vl_pk,
                 nullptr, nullptr, nullptr, nullptr, ms_bf, mv_bf, P);
        gemm2(ms_bf, wt(W_PM_GW1, l), pm_gb1 + (size_t)l * 2 * F, h_bf, P, 256, 128, 1, 1);
        gemm2(h_bf, wt(W_PM_GW2, l), pm_gb2 + (size_t)l * 2 * F, gate_bf, P, 256, 256, 2, 1);
        k_blend<<<(P * F + 255) / 256, 256, 0, stream>>>(gate_bf, ms_bf, mv_bf, ps, pv, pv_bf, P);
        gemm2(pv_bf, wt(W_PU_U, l), nullptr, Uv_bf, 3 * P, 128, 128, 0, 1,
              wt(W_PU_V, l), Vv_bf);
        k_catnorm<<<(P * F + 255) / 256, 256, 0, stream>>>(ps, Vv_bf, cat_bf, P);
        gemm2(cat_bf, wt(W_PU_W1, l), pu_b1 + (size_t)l * F, h_bf, P, 128, 256, 1, 1);
        gemm2(h_bf, wt(W_PU_W2, l), pu_b2 + (size_t)l * 3 * F, abuf_bf, P, 384, 128, 0, 1);
        k_update<<<(P * F + 255) / 256, 256, 0, stream>>>(ps, pv, abuf_bf, Uv_bf, Vv_bf,
                 ps, pv, nullptr, nullptr, P);
    }
}

// Round 7
// 1091.501 us; speedup vs baseline: 1.5097x; 1.1107x over previous
//
#include <hip/hip_runtime.h>
#include <hip/hip_bf16.h>
#include <math.h>

#define PI_F 3.14159265358979323846f

static constexpr int F = 128;
static constexpr int KB = 30;      // sinc basis size
static constexpr int LAYERS = 3;
static constexpr float CUT = 4.0f;
static constexpr int BINS = 512;   // table bins; built rows = BINS+1

typedef short bf16x8 __attribute__((ext_vector_type(8)));
typedef float f32x4 __attribute__((ext_vector_type(4)));
typedef unsigned short u16x8 __attribute__((ext_vector_type(8)));

__device__ __forceinline__ float bf2f(unsigned short u) {
    union { unsigned int i; float f; } c; c.i = ((unsigned int)u) << 16; return c.f;
}
__device__ __forceinline__ short f2bf(float x) {
    union { float f; unsigned int u; } c; c.f = x;
    unsigned int r = c.u + 0x7FFFu + ((c.u >> 16) & 1u);
    return (short)(r >> 16);
}

__device__ __forceinline__ float edge_dist(const float* __restrict__ sxyz,
                                           const float* __restrict__ dxyz,
                                           const float* __restrict__ disp,
                                           const float* __restrict__ cell,
                                           int s, int d, int e, float* dx) {
    const float* dp = disp + 3 * (size_t)e;
#pragma unroll
    for (int i = 0; i < 3; i++) {
        float dc = dp[0] * cell[0 * 3 + i] + dp[1] * cell[1 * 3 + i] + dp[2] * cell[2 * 3 + i];
        dx[i] = dxyz[3 * d + i] - (sxyz[3 * s + i] + dc);
    }
    return sqrtf(dx[0] * dx[0] + dx[1] * dx[1] + dx[2] * dx[2]);
}

// ---------------- CSR build (cutoff-filtered) ----------------
__global__ void k_count(const int* __restrict__ edges, const float* __restrict__ sxyz,
                        const float* __restrict__ dxyz, const float* __restrict__ disp,
                        const float* __restrict__ cell, int* __restrict__ cnt, int E) {
    int i = blockIdx.x * blockDim.x + threadIdx.x;
    if (i >= E) return;
    int s = edges[2 * i], d = edges[2 * i + 1];
    float dx[3];
    float dist = edge_dist(sxyz, dxyz, disp, cell, s, d, i, dx);
    if (dist < CUT) atomicAdd(&cnt[d], 1);
}

__global__ void k_scan(const int* __restrict__ cnt, int* __restrict__ off, int n) {
    __shared__ int part[1024];
    int t = threadIdx.x;
    int chunk = (n + 1023) / 1024;
    int b = t * chunk; if (b > n) b = n;
    int e = b + chunk; if (e > n) e = n;
    int s = 0;
    for (int i = b; i < e; i++) s += cnt[i];
    part[t] = s;
    __syncthreads();
    for (int o = 1; o < 1024; o <<= 1) {
        int v = part[t];
        int add = (t >= o) ? part[t - o] : 0;
        __syncthreads();
        part[t] = v + add;
        __syncthreads();
    }
    int run = (t == 0) ? 0 : part[t - 1];
    for (int i = b; i < e; i++) { off[i] = run; run += cnt[i]; }
    if (t == 1023) off[n] = part[1023];
}

__global__ void k_scatter(const int* __restrict__ edges, const float* __restrict__ sxyz,
                          const float* __restrict__ dxyz, const float* __restrict__ disp,
                          const float* __restrict__ cell, int* __restrict__ cur,
                          int* __restrict__ eids, int E) {
    int i = blockIdx.x * blockDim.x + threadIdx.x;
    if (i >= E) return;
    int s = edges[2 * i], d = edges[2 * i + 1];
    float dx[3];
    float dist = edge_dist(sxyz, dxyz, disp, cell, s, d, i, dx);
    if (dist < CUT) {
        int pos = atomicAdd(&cur[d], 1);
        eids[pos] = i;
    }
}

// ---------------- edge records, CSR-ordered: float4(u0,u1,u2, dist*BINS/CUT) ----------------
__global__ void k_geom_rec(const float* __restrict__ sxyz, const float* __restrict__ dxyz,
                           const float* __restrict__ disp, const float* __restrict__ cell,
                           const int* __restrict__ edges, const int* __restrict__ eids,
                           const int* __restrict__ eoff, int ndst,
                           float4* __restrict__ erec, int* __restrict__ srcs) {
    int pos = blockIdx.x * blockDim.x + threadIdx.x;
    if (pos >= eoff[ndst]) return;
    int e = eids[pos];
    int s = edges[2 * e], d = edges[2 * e + 1];
    float dx[3];
    float dist = edge_dist(sxyz, dxyz, disp, cell, s, d, e, dx);
    float inv = 1.0f / fmaxf(dist, 1e-12f);
    float db = fminf(dist * ((float)BINS / CUT), (float)BINS - 0.0001f);
    erec[pos] = make_float4(dx[0] * inv, dx[1] * inv, dx[2] * inv, db);
    srcs[pos] = s;
}

// ---------------- S' basis ----------------
__global__ void k_sbuild(float* __restrict__ Sp) {
    int i = blockIdx.x * blockDim.x + threadIdx.x;
    if (i > BINS) return;
    float d = (float)i * (CUT / (float)BINS);
    float cc = (d < CUT) ? 0.5f * (cosf(PI_F * d / CUT) + 1.0f) : 0.0f;
    float* row = Sp + (size_t)i * 32;
#pragma unroll
    for (int k = 0; k < KB; k++) {
        float kk = (float)(k + 1);
        float st = (d > 1e-12f) ? sinf(PI_F * d * kk / CUT) / d : PI_F * kk / CUT;
        row[k] = cc * st;
    }
    row[30] = cc;
    row[31] = 0.f;
}

// ---------------- assemble fw' (6 tables x 32 x 384) ----------------
__global__ void k_fwpack(const float* __restrict__ ai_fw, const float* __restrict__ ai_fb,
                         const float* __restrict__ pm_fw, const float* __restrict__ pm_fb,
                         float* __restrict__ fwp) {
    int i = blockIdx.x * blockDim.x + threadIdx.x;
    if (i >= 6 * 32 * 384) return;
    int tbl = i / (32 * 384);
    int k = (i / 384) % 32;
    int c = i % 384;
    const float* fw = (tbl < 3) ? ai_fw + (size_t)tbl * KB * 384 : pm_fw + (size_t)(tbl - 3) * KB * 384;
    const float* fb = (tbl < 3) ? ai_fb + (size_t)tbl * 384 : pm_fb + (size_t)(tbl - 3) * 384;
    float v = 0.f;
    if (k < KB) v = fw[(size_t)k * 384 + c];
    else if (k == 30) v = fb[c];
    fwp[i] = v;
}

// ---------------- interleave table pairs: Tbf[513][512] -> Tp[512][128][8] ----------------
__global__ void k_tpack(const short* __restrict__ Tbf, short* __restrict__ Tp) {
    int i = blockIdx.x * blockDim.x + threadIdx.x;
    if (i >= 6 * BINS * 128) return;
    int tbl = i / (BINS * 128);
    int rem = i % (BINS * 128);
    int bin = rem >> 7, lane = rem & 127;
    const short* a = Tbf + ((size_t)tbl * (BINS + 1) + bin) * 512 + lane * 4;
    const short* b = a + 512;
    short* o = Tp + ((size_t)tbl * BINS + bin) * 1024 + lane * 8;
    o[0] = a[0]; o[1] = a[1]; o[2] = a[2]; o[3] = 0;
    o[4] = b[0]; o[5] = b[1]; o[6] = b[2]; o[7] = 0;
}

// ---------------- weight transpose+cvt: src f32 [K][N] (xL) -> dst bf16 [N][K] ----------------
struct CvtArgs {
    const float* src[14];
    int dstoff[14];
    int Kk[14];
    int Nn[14];
};
__global__ __launch_bounds__(256) void k_cvtw(CvtArgs a, short* __restrict__ dst) {
    int arr = blockIdx.y, l = blockIdx.z;
    int K = a.Kk[arr], N = a.Nn[arr];
    int tilesx = N / 32, tilesy = K / 32;
    int tile = blockIdx.x;
    if (tile >= tilesx * tilesy) return;
    int tn = (tile % tilesx) * 32, tk = (tile / tilesx) * 32;
    __shared__ float tb[32][33];
    int tx = threadIdx.x & 31, ty = threadIdx.x >> 5;  // 32 x 8
    const float* src = a.src[arr] + (size_t)l * K * N;
    short* d = dst + a.dstoff[arr] + (size_t)l * K * N;
#pragma unroll
    for (int r = 0; r < 4; r++)
        tb[ty * 4 + r][tx] = src[(size_t)(tk + ty * 4 + r) * N + tn + tx];
    __syncthreads();
#pragma unroll
    for (int r = 0; r < 4; r++)
        d[(size_t)(tn + ty * 4 + r) * K + tk + tx] = f2bf(tb[tx][ty * 4 + r]);
}

// ---------------- init: s0 = embed[Z] (f32 + bf16) ----------------
__global__ void k_embed(const int* __restrict__ Z, const float* __restrict__ emb,
                        float* __restrict__ s, short* __restrict__ sbf, int n) {
    int i = blockIdx.x * blockDim.x + threadIdx.x;
    if (i < n * F) {
        float v = emb[(size_t)Z[i / F] * F + (i % F)];
        s[i] = v; sbf[i] = f2bf(v);
    }
}

// ---------------- f32 VALU GEMM (table build only) ----------------
// outmode 4: bf16 packed512 with z-stride.
__global__ __launch_bounds__(256) void k_gemm(const float* __restrict__ A, const float* __restrict__ B,
                                              void* __restrict__ Cout,
                                              int M, int N, int K, int outmode,
                                              int bstride, int cstride) {
    __shared__ float As[16][64];
    __shared__ float Bs[16][64];
    const float* Bz = B + (size_t)blockIdx.z * bstride;
    int tid = threadIdx.x;
    int bm = blockIdx.y * 64, bn = blockIdx.x * 64;
    int tx = tid & 15, ty = tid >> 4;
    float acc[4][4] = {};
    int arow = tid >> 2;
    int acol = (tid & 3) * 4;
    int brow = tid >> 4;
    int bcol = (tid & 15) * 4;
    for (int k0 = 0; k0 < K; k0 += 16) {
        float4 av = make_float4(0.f, 0.f, 0.f, 0.f);
        int gm = bm + arow;
        if (gm < M) av = *reinterpret_cast<const float4*>(A + (size_t)gm * K + k0 + acol);
        As[acol + 0][arow] = av.x; As[acol + 1][arow] = av.y;
        As[acol + 2][arow] = av.z; As[acol + 3][arow] = av.w;
        float4 bv = *reinterpret_cast<const float4*>(Bz + (size_t)(k0 + brow) * N + bn + bcol);
        Bs[brow][bcol + 0] = bv.x; Bs[brow][bcol + 1] = bv.y;
        Bs[brow][bcol + 2] = bv.z; Bs[brow][bcol + 3] = bv.w;
        __syncthreads();
#pragma unroll
        for (int k = 0; k < 16; k++) {
            float a0 = As[k][ty * 4 + 0], a1 = As[k][ty * 4 + 1];
            float a2 = As[k][ty * 4 + 2], a3 = As[k][ty * 4 + 3];
            float b0 = Bs[k][tx * 4 + 0], b1 = Bs[k][tx * 4 + 1];
            float b2 = Bs[k][tx * 4 + 2], b3 = Bs[k][tx * 4 + 3];
            acc[0][0] += a0 * b0; acc[0][1] += a0 * b1; acc[0][2] += a0 * b2; acc[0][3] += a0 * b3;
            acc[1][0] += a1 * b0; acc[1][1] += a1 * b1; acc[1][2] += a1 * b2; acc[1][3] += a1 * b3;
            acc[2][0] += a2 * b0; acc[2][1] += a2 * b1; acc[2][2] += a2 * b2; acc[2][3] += a2 * b3;
            acc[3][0] += a3 * b0; acc[3][1] += a3 * b1; acc[3][2] += a3 * b2; acc[3][3] += a3 * b3;
        }
        __syncthreads();
    }
#pragma unroll
    for (int i = 0; i < 4; i++) {
        int gm = bm + ty * 4 + i;
        if (gm >= M) continue;
#pragma unroll
        for (int j = 0; j < 4; j++) {
            int gn = bn + tx * 4 + j;
            float v = acc[i][j];
            if (outmode == 0) ((float*)Cout)[(size_t)gm * N + gn] = v;
            else ((short*)Cout)[(size_t)blockIdx.z * cstride + (size_t)gm * 512 + (gn & 127) * 4 + (gn >> 7)] = f2bf(v);
        }
    }
}

// ---------------- bf16 MFMA GEMM, weights-stationary-in-cache, no LDS/barriers ----------------
// A: [M][K] bf16 rm. Bt: [N][K] bf16 rm. N%64==0, K%32==0.
// act: 0 none, 1 silu, 2 sigmoid. outmode: 0 f32 flat, 1 bf16 flat, 2 bf16 packed1024 (slots 0-3).
// z-batching via element strides azs/bzs/czs/biaszs.
__global__ __launch_bounds__(256) void k_gemm2(
    const short* __restrict__ A, const short* __restrict__ Bt,
    const float* __restrict__ bias, void* __restrict__ C,
    int M, int N, int K, int act, int outmode,
    long azs, long bzs, long czs, long biaszs) {
    const int z = blockIdx.z;
    const short* __restrict__ Az = A + (size_t)z * azs;
    const short* __restrict__ B = Bt + (size_t)z * bzs;
    const float* __restrict__ bi = bias ? bias + (size_t)z * biaszs : nullptr;
    const size_t coff = (size_t)z * czs;
    const int lane = threadIdx.x & 63, wave = threadIdx.x >> 6;
    const int l15 = lane & 15, l16 = lane >> 4;
    const int row0 = blockIdx.y * 256 + wave * 64;
    const int col0 = blockIdx.x * 64;
    if (row0 >= M) return;
    f32x4 acc[4][4] = {};
    for (int k0 = 0; k0 < K; k0 += 32) {
        bf16x8 af[4], bfr[4];
#pragma unroll
        for (int i = 0; i < 4; i++) {
            int r = row0 + i * 16 + l15;
            bf16x8 t = {};
            if (r < M) t = *reinterpret_cast<const bf16x8*>(Az + (size_t)r * K + k0 + l16 * 8);
            af[i] = t;
        }
#pragma unroll
        for (int j = 0; j < 4; j++) {
            int c = col0 + j * 16 + l15;
            bfr[j] = *reinterpret_cast<const bf16x8*>(B + (size_t)c * K + k0 + l16 * 8);
        }
#pragma unroll
        for (int i = 0; i < 4; i++)
#pragma unroll
            for (int j = 0; j < 4; j++)
                acc[i][j] = __builtin_amdgcn_mfma_f32_16x16x32_bf16(af[i], bfr[j], acc[i][j], 0, 0, 0);
    }
#pragma unroll
    for (int j = 0; j < 4; j++) {
        int gn = col0 + j * 16 + l15;
        float bb = bi ? bi[gn] : 0.f;
#pragma unroll
        for (int i = 0; i < 4; i++) {
#pragma unroll
            for (int r = 0; r < 4; r++) {
                int gm = row0 + i * 16 + l16 * 4 + r;
                if (gm >= M) continue;
                float v = acc[i][j][r] + bb;
                if (act == 1) v = v / (1.0f + expf(-v));
                else if (act == 2) v = 1.0f / (1.0f + expf(-v));
                if (outmode == 0) ((float*)C)[coff + (size_t)gm * N + gn] = v;
                else if (outmode == 1) ((short*)C)[coff + (size_t)gm * N + gn] = f2bf(v);
                else ((short*)C)[coff + (size_t)gm * 1024 + (gn & 127) * 8 + (gn >> 7)] = f2bf(v);
            }
        }
    }
}

// ---------------- fused edge messages + segment sum ----------------
// PV[node][128][8]: slots 0-2 phi, 4-6 vsend.  Tp[bin][128][8]: slots 0-2 row bin, 4-6 row bin+1.
__global__ __launch_bounds__(256) void k_gather(
    const float4* __restrict__ erec, const int* __restrict__ srcs,
    const int* __restrict__ eoff, const short* __restrict__ Tp,
    const short* __restrict__ PV,
    const float* __restrict__ s_in, const float* __restrict__ v_in,
    float* __restrict__ s_out, float* __restrict__ v_out,
    short* __restrict__ s_out_bf, short* __restrict__ v_out_bf, int ndst) {
    const int t = threadIdx.x & 127;
    const int half = threadIdx.x >> 7;

    for (int d = blockIdx.x * 2 + half; d < ndst; d += gridDim.x * 2) {
        const int e0 = eoff[d], e1 = eoff[d + 1];
        float accs = 0.f, av0 = 0.f, av1 = 0.f, av2 = 0.f;

        auto ACC = [&](const float4& u, int bin, u16x8 T, u16x8 Pv) {
            const float fr = u.w - (float)bin;
            const float f0 = fmaf(fr, bf2f(T[4]) - bf2f(T[0]), bf2f(T[0]));
            const float f1 = fmaf(fr, bf2f(T[5]) - bf2f(T[1]), bf2f(T[1]));
            const float f2 = fmaf(fr, bf2f(T[6]) - bf2f(T[2]), bf2f(T[2]));
            const float gsv = f0 * bf2f(Pv[0]);
            const float gev = f1 * bf2f(Pv[1]);
            accs += f2 * bf2f(Pv[2]);
            av0 = fmaf(bf2f(Pv[4]), gsv, fmaf(gev, u.x, av0));
            av1 = fmaf(bf2f(Pv[5]), gsv, fmaf(gev, u.y, av1));
            av2 = fmaf(bf2f(Pv[6]), gsv, fmaf(gev, u.z, av2));
        };

        int ii = e0;
        for (; ii + 3 < e1; ii += 4) {
            const float4 u0 = erec[ii + 0], u1 = erec[ii + 1];
            const float4 u2 = erec[ii + 2], u3 = erec[ii + 3];
            const int s0 = srcs[ii + 0], s1 = srcs[ii + 1];
            const int s2 = srcs[ii + 2], s3 = srcs[ii + 3];
            const int b0 = (int)u0.w, b1 = (int)u1.w, b2 = (int)u2.w, b3 = (int)u3.w;
            const u16x8 T0 = *(const u16x8*)(Tp + ((size_t)b0 * 128 + t) * 8);
            const u16x8 T1 = *(const u16x8*)(Tp + ((size_t)b1 * 128 + t) * 8);
            const u16x8 T2 = *(const u16x8*)(Tp + ((size_t)b2 * 128 + t) * 8);
            const u16x8 T3 = *(const u16x8*)(Tp + ((size_t)b3 * 128 + t) * 8);
            const u16x8 P0 = *(const u16x8*)(PV + ((size_t)s0 * 128 + t) * 8);
            const u16x8 P1 = *(const u16x8*)(PV + ((size_t)s1 * 128 + t) * 8);
            const u16x8 P2 = *(const u16x8*)(PV + ((size_t)s2 * 128 + t) * 8);
            const u16x8 P3 = *(const u16x8*)(PV + ((size_t)s3 * 128 + t) * 8);
            ACC(u0, b0, T0, P0); ACC(u1, b1, T1, P1);
            ACC(u2, b2, T2, P2); ACC(u3, b3, T3, P3);
        }
        for (; ii < e1; ++ii) {
            const float4 u = erec[ii];
            const int s = srcs[ii];
            const int b = (int)u.w;
            const u16x8 T = *(const u16x8*)(Tp + ((size_t)b * 128 + t) * 8);
            const u16x8 P = *(const u16x8*)(PV + ((size_t)s * 128 + t) * 8);
            ACC(u, b, T, P);
        }

        if (s_in) {
            accs += s_in[(size_t)d * 128 + t];
            av0 += v_in[(size_t)d * 384 + t];
            av1 += v_in[(size_t)d * 384 + 128 + t];
            av2 += v_in[(size_t)d * 384 + 256 + t];
        }
        if (s_out) {
            s_out[(size_t)d * 128 + t] = accs;
            v_out[(size_t)d * 384 + t] = av0;
            v_out[(size_t)d * 384 + 128 + t] = av1;
            v_out[(size_t)d * 384 + 256 + t] = av2;
        }
        if (s_out_bf) s_out_bf[(size_t)d * 128 + t] = f2bf(accs);
        if (v_out_bf) {
            v_out_bf[(size_t)(3 * d + 0) * 128 + t] = f2bf(av0);
            v_out_bf[(size_t)(3 * d + 1) * 128 + t] = f2bf(av1);
            v_out_bf[(size_t)(3 * d + 2) * 128 + t] = f2bf(av2);
        }
    }
}

// ---------------- cat = [s, ||Vv||_axis1] -> bf16 ----------------
__global__ void k_catnorm(const float* __restrict__ s, const short* __restrict__ Vv,
                          short* __restrict__ cat, int n) {
    int i = blockIdx.x * blockDim.x + threadIdx.x;
    if (i >= n * F) return;
    int nn = i / F, g = i % F;
    float w0 = bf2f(Vv[(size_t)(3 * nn + 0) * 128 + g]);
    float w1 = bf2f(Vv[(size_t)(3 * nn + 1) * 128 + g]);
    float w2 = bf2f(Vv[(size_t)(3 * nn + 2) * 128 + g]);
    cat[(size_t)nn * 256 + g] = f2bf(s[i]);
    cat[(size_t)nn * 256 + 128 + g] = f2bf(sqrtf(w0 * w0 + w1 * w1 + w2 * w2));
}

// ---------------- painn update (v copy into PV slots 4-6 of next ring buffer) ----------------
__global__ void k_update(const float* __restrict__ s_in, const float* __restrict__ v_in,
                         const short* __restrict__ a, const short* __restrict__ Uv,
                         const short* __restrict__ Vv,
                         float* __restrict__ s_out, float* __restrict__ v_out,
                         short* __restrict__ s_out_bf, short* __restrict__ v_out_pk, int n) {
    int i = blockIdx.x * blockDim.x + threadIdx.x;
    if (i >= n * F) return;
    int nn = i / F, g = i % F;
    size_t b = (size_t)nn * 384;
    float u0 = bf2f(Uv[(size_t)(3 * nn + 0) * 128 + g]);
    float u1 = bf2f(Uv[(size_t)(3 * nn + 1) * 128 + g]);
    float u2 = bf2f(Uv[(size_t)(3 * nn + 2) * 128 + g]);
    float w0 = bf2f(Vv[(size_t)(3 * nn + 0) * 128 + g]);
    float w1 = bf2f(Vv[(size_t)(3 * nn + 1) * 128 + g]);
    float w2 = bf2f(Vv[(size_t)(3 * nn + 2) * 128 + g]);
    float inner = u0 * w0 + u1 * w1 + u2 * w2;
    float ass = bf2f(a[b + g]), asv = bf2f(a[b + 128 + g]), avv = bf2f(a[b + 256 + g]);
    float snew = s_in[i] + ass + asv * inner;
    s_out[i] = snew;
    float r0 = v_in[b + g] + avv * u0;
    float r1 = v_in[b + 128 + g] + avv * u1;
    float r2 = v_in[b + 256 + g] + avv * u2;
    v_out[b + g] = r0;
    v_out[b + 128 + g] = r1;
    v_out[b + 256 + g] = r2;
    if (s_out_bf) s_out_bf[i] = f2bf(snew);
    if (v_out_pk) {
        size_t pb = (size_t)nn * 1024 + (size_t)g * 8;
        v_out_pk[pb + 4] = f2bf(r0);
        v_out_pk[pb + 5] = f2bf(r1);
        v_out_pk[pb + 6] = f2bf(r2);
    }
}

// ---------------- gated blend ----------------
__global__ void k_blend(const short* __restrict__ gate, const short* __restrict__ ms,
                        const short* __restrict__ mv, float* __restrict__ ps,
                        float* __restrict__ pv, short* __restrict__ pv_bf, int n) {
    int i = blockIdx.x * blockDim.x + threadIdx.x;
    if (i >= n * F) return;
    int p = i / F, g = i % F;
    float gs = bf2f(gate[(size_t)p * 256 + g]);
    float gv = bf2f(gate[(size_t)p * 256 + 128 + g]);
    ps[i] = ps[i] * gs + (1.0f - gs) * bf2f(ms[(size_t)p * 128 + g]);
    size_t b = (size_t)p * 384;
#pragma unroll
    for (int i3 = 0; i3 < 3; i3++) {
        size_t o = b + (size_t)i3 * 128 + g;
        float val = pv[o] * gv + (1.0f - gv) * bf2f(mv[(size_t)(3 * p + i3) * 128 + g]);
        pv[o] = val;
        pv_bf[(size_t)(3 * p + i3) * 128 + g] = f2bf(val);
    }
}

extern "C" void kernel_launch(void* const* d_in, const int* in_sizes, int n_in,
                              void* d_out, int out_size, void* d_ws, size_t ws_size,
                              hipStream_t stream) {
    const float* atom_xyz  = (const float*)d_in[0];
    const float* probe_xyz = (const float*)d_in[1];
    const float* cell      = (const float*)d_in[2];
    const float* a_disp    = (const float*)d_in[3];
    const float* p_disp    = (const float*)d_in[4];
    const float* atom_embed= (const float*)d_in[5];
    const float* ai_fw = (const float*)d_in[6];
    const float* ai_fb = (const float*)d_in[7];
    const float* ai_b1 = (const float*)d_in[9];
    const float* ai_b2 = (const float*)d_in[11];
    const float* au_b1 = (const float*)d_in[15];
    const float* au_b2 = (const float*)d_in[17];
    const float* pm_fw = (const float*)d_in[18];
    const float* pm_fb = (const float*)d_in[19];
    const float* pm_b1 = (const float*)d_in[21];
    const float* pm_b2 = (const float*)d_in[23];
    const float* pm_gb1= (const float*)d_in[25];
    const float* pm_gb2= (const float*)d_in[27];
    const float* pu_b1 = (const float*)d_in[31];
    const float* pu_b2 = (const float*)d_in[33];
    const int* nodes_Z = (const int*)d_in[34];
    const int* a_edges = (const int*)d_in[35];
    const int* p_edges = (const int*)d_in[36];

    const int N  = in_sizes[34];
    const int EA = in_sizes[35] / 2;
    const int EP = in_sizes[36] / 2;
    const int P  = in_sizes[1] / 3;

    enum { W_AI_W1=0, W_AI_W2, W_AU_U, W_AU_V, W_AU_W1, W_AU_W2, W_PM_W1, W_PM_W2,
           W_PM_GW1, W_PM_GW2, W_PU_U, W_PU_V, W_PU_W1, W_PU_W2 };
    const int wsrc[14] = {8,10,12,13,14,16,20,22,24,26,28,29,30,32};
    const int wK[14]   = {128,128,128,128,256,128,128,128,128,256,128,128,256,128};
    const int wN[14]   = {128,384,128,128,128,384,128,384,256,256,128,128,128,384};
    size_t woff[15]; woff[0] = 0;
    for (int i = 0; i < 14; i++) woff[i + 1] = woff[i] + (size_t)3 * wK[i] * wN[i];

    char* w = (char*)d_ws;
    size_t off = 0;
    auto alloc = [&](size_t bytes) -> void* {
        void* p = w + off;
        off = (off + bytes + 255) & ~(size_t)255;
        return p;
    };
    int* a_off  = (int*)alloc((size_t)(N + 1) * 4);
    int* a_cur  = (int*)alloc((size_t)N * 4);
    int* a_eids = (int*)alloc((size_t)EA * 4);
    int* a_srcs = (int*)alloc((size_t)EA * 4);
    int* p_off  = (int*)alloc((size_t)(P + 1) * 4);
    int* p_cur  = (int*)alloc((size_t)P * 4);
    int* p_eids = (int*)alloc((size_t)EP * 4);
    int* p_srcs = (int*)alloc((size_t)EP * 4);
    float4* a_erec = (float4*)alloc((size_t)EA * 16);
    float4* p_erec = (float4*)alloc((size_t)EP * 16);
    float* Sp   = (float*)alloc((size_t)(BINS + 1) * 32 * 4);
    float* fwp  = (float*)alloc((size_t)6 * 32 * 384 * 4);
    short* Tbf  = (short*)alloc((size_t)6 * (BINS + 1) * 512 * 2);
    short* Tp   = (short*)alloc((size_t)6 * BINS * 1024 * 2);
    short* wbt  = (short*)alloc(woff[14] * 2);
    float* s0     = (float*)alloc((size_t)N * F * 4);
    float* v0     = (float*)alloc((size_t)N * 3 * F * 4);
    float* s_list = (float*)alloc((size_t)LAYERS * N * F * 4);
    float* v_list = (float*)alloc((size_t)LAYERS * N * 3 * F * 4);
    float* msf    = (float*)alloc((size_t)N * F * 4);
    float* mvf    = (float*)alloc((size_t)N * 3 * F * 4);
    short* s0_bf    = (short*)alloc((size_t)N * F * 2);
    short* sbf_list = (short*)alloc((size_t)LAYERS * N * F * 2);
    short* vpk8     = (short*)alloc((size_t)4 * N * 1024 * 2);  // PV ring: buf(-1..2)
    short* h3_bf    = (short*)alloc((size_t)3 * N * F * 2);
    short* ms_bf    = (short*)alloc((size_t)P * F * 2);
    short* mv_bf    = (short*)alloc((size_t)P * 3 * F * 2);
    short* h_bf     = (short*)alloc((size_t)P * 2 * F * 2);
    short* gate_bf  = (short*)alloc((size_t)P * 2 * F * 2);
    short* cat_bf   = (short*)alloc((size_t)P * 2 * F * 2);
    short* abuf_bf  = (short*)alloc((size_t)P * 3 * F * 2);
    short* UVv_bf   = (short*)alloc((size_t)2 * 3 * P * F * 2);
    short* pv_bf    = (short*)alloc((size_t)P * 3 * F * 2);
    short* Uv_bf = UVv_bf;
    short* Vv_bf = UVv_bf + (size_t)3 * P * F;
    (void)ws_size; (void)n_in;

    // CSR atoms (cutoff-filtered)
    hipMemsetAsync(a_cur, 0, (size_t)N * 4, stream);
    k_count<<<(EA + 255) / 256, 256, 0, stream>>>(a_edges, atom_xyz, atom_xyz, a_disp, cell, a_cur, EA);
    k_scan<<<1, 1024, 0, stream>>>(a_cur, a_off, N);
    hipMemcpyAsync(a_cur, a_off, (size_t)N * 4, hipMemcpyDeviceToDevice, stream);
    k_scatter<<<(EA + 255) / 256, 256, 0, stream>>>(a_edges, atom_xyz, atom_xyz, a_disp, cell, a_cur, a_eids, EA);
    // CSR probes
    hipMemsetAsync(p_cur, 0, (size_t)P * 4, stream);
    k_count<<<(EP + 255) / 256, 256, 0, stream>>>(p_edges, atom_xyz, probe_xyz, p_disp, cell, p_cur, EP);
    k_scan<<<1, 1024, 0, stream>>>(p_cur, p_off, P);
    hipMemcpyAsync(p_cur, p_off, (size_t)P * 4, hipMemcpyDeviceToDevice, stream);
    k_scatter<<<(EP + 255) / 256, 256, 0, stream>>>(p_edges, atom_xyz, probe_xyz, p_disp, cell, p_cur, p_eids, EP);

    // edge records (CSR-ordered)
    k_geom_rec<<<(EA + 255) / 256, 256, 0, stream>>>(atom_xyz, atom_xyz, a_disp, cell, a_edges,
                                                     a_eids, a_off, N, a_erec, a_srcs);
    k_geom_rec<<<(EP + 255) / 256, 256, 0, stream>>>(atom_xyz, probe_xyz, p_disp, cell, p_edges,
                                                     p_eids, p_off, P, p_erec, p_srcs);

    // filter tables -> bf16 packed512 -> interleaved pairs
    k_sbuild<<<(BINS + 256) / 256, 256, 0, stream>>>(Sp);
    k_fwpack<<<(6 * 32 * 384 + 255) / 256, 256, 0, stream>>>(ai_fw, ai_fb, pm_fw, pm_fb, fwp);
    {
        dim3 g(384 / 64, (BINS + 1 + 63) / 64, 6);
        k_gemm<<<g, 256, 0, stream>>>(Sp, fwp, Tbf, BINS + 1, 384, 32, 4, 32 * 384, (BINS + 1) * 512);
    }
    k_tpack<<<(6 * BINS * 128 + 255) / 256, 256, 0, stream>>>(Tbf, Tp);

    // weights -> bf16 transposed
    {
        CvtArgs ca;
        for (int i = 0; i < 14; i++) {
            ca.src[i] = (const float*)d_in[wsrc[i]];
            ca.dstoff[i] = (int)woff[i];
            ca.Kk[i] = wK[i]; ca.Nn[i] = wN[i];
        }
        k_cvtw<<<dim3(64, 14, 3), 256, 0, stream>>>(ca, wbt);
    }
    auto wt = [&](int a, int l) { return wbt + woff[a] + (size_t)l * wK[a] * wN[a]; };

    // init node states
    k_embed<<<(N * F + 255) / 256, 256, 0, stream>>>(nodes_Z, atom_embed, s0, s0_bf, N);
    hipMemsetAsync(v0, 0, (size_t)N * 3 * F * 4, stream);
    hipMemsetAsync(vpk8, 0, (size_t)N * 1024 * 2, stream);  // buf(-1): v slots = 0

    auto gemm2 = [&](const short* A, const short* Bt, const float* bias, void* C,
                     int M, int Nc, int K, int act, int outmode,
                     int nz = 1, long azs = 0, long bzs = 0, long czs = 0, long biaszs = 0) {
        dim3 g(Nc / 64, (M + 255) / 256, nz);
        k_gemm2<<<g, 256, 0, stream>>>(A, Bt, bias, C, M, Nc, K, act, outmode, azs, bzs, czs, biaszs);
    };
    auto pvbuf = [&](int idx) { return vpk8 + (size_t)idx * N * 1024; };  // idx = layer+1

    // ---- atom message-passing layers ----
    for (int l = 0; l < LAYERS; l++) {
        const float* scur = l ? (s_list + (size_t)(l - 1) * N * F) : s0;
        const float* vcur = l ? (v_list + (size_t)(l - 1) * N * 3 * F) : v0;
        const short* scur_bf = l ? (sbf_list + (size_t)(l - 1) * N * F) : s0_bf;
        gemm2(scur_bf, wt(W_AI_W1, l), ai_b1 + (size_t)l * F, h_bf, N, 128, 128, 1, 1);
        gemm2(h_bf, wt(W_AI_W2, l), ai_b2 + (size_t)l * 3 * F, pvbuf(l), N, 384, 128, 0, 2);
        k_gather<<<(N + 1) / 2, 256, 0, stream>>>(a_erec, a_srcs, a_off,
                 Tp + (size_t)l * BINS * 1024, pvbuf(l),
                 scur, vcur, msf, mvf, nullptr, mv_bf, N);
        gemm2(mv_bf, wt(W_AU_U, l), nullptr, UVv_bf, 3 * N, 128, 128, 0, 1,
              2, 0, (long)(woff[W_AU_V] - woff[W_AU_U]), (long)3 * P * F, 0);
        k_catnorm<<<(N * F + 255) / 256, 256, 0, stream>>>(msf, Vv_bf, cat_bf, N);
        gemm2(cat_bf, wt(W_AU_W1, l), au_b1 + (size_t)l * F, h_bf, N, 128, 256, 1, 1);
        gemm2(h_bf, wt(W_AU_W2, l), au_b2 + (size_t)l * 3 * F, abuf_bf, N, 384, 128, 0, 1);
        k_update<<<(N * F + 255) / 256, 256, 0, stream>>>(msf, mvf, abuf_bf, Uv_bf, Vv_bf,
                 s_list + (size_t)l * N * F, v_list + (size_t)l * N * 3 * F,
                 sbf_list + (size_t)l * N * F, pvbuf(l + 1), N);
    }

    // ---- probe phase ----
    float* ps = (float*)d_out;
    float* pv = (float*)d_out + (size_t)P * F;
    hipMemsetAsync(d_out, 0, (size_t)out_size * 4, stream);

    // batched probe phi (all 3 layers): phi(l) -> pvbuf(l+1) slots 0-3
    gemm2(sbf_list, wt(W_PM_W1, 0), pm_b1, h3_bf, N, 128, 128, 1, 1,
          3, (long)N * F, (long)128 * 128, (long)N * F, 128);
    gemm2(h3_bf, wt(W_PM_W2, 0), pm_b2, pvbuf(1), N, 384, 128, 0, 2,
          3, (long)N * F, (long)128 * 384, (long)N * 1024, 384);

    for (int l = 0; l < LAYERS; l++) {
        k_gather<<<(P + 1) / 2, 256, 0, stream>>>(p_erec, p_srcs, p_off,
                 Tp + (size_t)(3 + l) * BINS * 1024, pvbuf(l + 1),
                 nullptr, nullptr, nullptr, nullptr, ms_bf, mv_bf, P);
        gemm2(ms_bf, wt(W_PM_GW1, l), pm_gb1 + (size_t)l * 2 * F, h_bf, P, 256, 128, 1, 1);
        gemm2(h_bf, wt(W_PM_GW2, l), pm_gb2 + (size_t)l * 2 * F, gate_bf, P, 256, 256, 2, 1);
        k_blend<<<(P * F + 255) / 256, 256, 0, stream>>>(gate_bf, ms_bf, mv_bf, ps, pv, pv_bf, P);
        gemm2(pv_bf, wt(W_PU_U, l), nullptr, UVv_bf, 3 * P, 128, 128, 0, 1,
              2, 0, (long)(woff[W_PU_V] - woff[W_PU_U]), (long)3 * P * F, 0);
        k_catnorm<<<(P * F + 255) / 256, 256, 0, stream>>>(ps, Vv_bf, cat_bf, P);
        gemm2(cat_bf, wt(W_PU_W1, l), pu_b1 + (size_t)l * F, h_bf, P, 128, 256, 1, 1);
        gemm2(h_bf, wt(W_PU_W2, l), pu_b2 + (size_t)l * 3 * F, abuf_bf, P, 384, 128, 0, 1);
        k_update<<<(P * F + 255) / 256, 256, 0, stream>>>(ps, pv, abuf_bf, Uv_bf, Vv_bf,
                 ps, pv, nullptr, nullptr, P);
    }
}